// Round 4
// baseline (324.420 us; speedup 1.0000x reference)
//
#include <hip/hip_runtime.h>
#include <stdint.h>

#define BB 2
#define HH 16
#define LL 2048
#define DD 1024
#define HDD 64
#define NC 512

typedef __bf16 bf16x8 __attribute__((ext_vector_type(8)));
typedef float f32x4 __attribute__((ext_vector_type(4)));
typedef unsigned short u16x8 __attribute__((ext_vector_type(8)));

__device__ __forceinline__ unsigned short f2bf(float f) {
  union { float f; unsigned u; } v; v.f = f;
  unsigned u = v.u;
  u += 0x7fffu + ((u >> 16) & 1u);
  return (unsigned short)(u >> 16);
}
__device__ __forceinline__ float bf2f(unsigned short h) {
  union { unsigned u; float f; } v; v.u = ((unsigned)h) << 16;
  return v.f;
}

// async global->LDS, 16B per lane; lds ptr must be wave-uniform base (HW adds lane*16)
__device__ __forceinline__ void load_lds16(const unsigned short* g, unsigned short* l) {
  __builtin_amdgcn_global_load_lds((const __attribute__((address_space(1))) void*)g,
                                   (__attribute__((address_space(3))) void*)l, 16, 0, 0);
}

// ---------------- cast kernel (adds x lo-split + wk lo-split + codebook lo-split) ----------------
__global__ void cast_all(const float* __restrict__ x, const float* __restrict__ wq,
                         const float* __restrict__ wk, const float* __restrict__ wv,
                         const float* __restrict__ wo, const float* __restrict__ cb,
                         unsigned short* __restrict__ xb, unsigned short* __restrict__ xl,
                         unsigned short* __restrict__ wb, unsigned short* __restrict__ wkl,
                         unsigned short* __restrict__ wob, unsigned short* __restrict__ cbb,
                         unsigned short* __restrict__ cbl, float* __restrict__ lsum) {
  long i = (long)blockIdx.x * blockDim.x + threadIdx.x;
  if (i == 0) lsum[0] = 0.f;
  const long NX = 4194304, NW = 1048576, NCB = 524288;
  const long TOT = NX + 4 * NW + NCB;
  for (long t = i; t < TOT; t += (long)gridDim.x * blockDim.x) {
    if (t < NX) {
      float v = x[t];
      unsigned short hi = f2bf(v);
      xb[t] = hi;
      xl[t] = f2bf(v - bf2f(hi));
    } else if (t < NX + NW) {
      wb[t - NX] = f2bf(wq[t - NX]);
    } else if (t < NX + 2 * NW) {
      long idx = t - NX - NW;
      float v = wk[idx];
      unsigned short hi = f2bf(v);
      wb[NW + idx] = hi;
      wkl[idx] = f2bf(v - bf2f(hi));
    } else if (t < NX + 3 * NW) {
      wb[t - NX] = f2bf(wv[t - NX - 2 * NW]);
    } else if (t < NX + 4 * NW) {
      wob[t - NX - 3 * NW] = f2bf(wo[t - NX - 3 * NW]);
    } else {
      long idx = t - NX - 4 * NW;
      float v = cb[idx];
      unsigned short hi = f2bf(v);
      cbb[idx] = hi;
      cbl[idx] = f2bf(v - bf2f(hi));
    }
  }
}

// ---------------- codebook norms (fp64 accumulate) ----------------
__global__ void c2_kernel(const float* __restrict__ cb, float* __restrict__ c2) {
  int i = blockIdx.x * blockDim.x + threadIdx.x;
  if (i >= HH * NC) return;
  const float* r = cb + (long)i * HDD;
  double s = 0.0;
  for (int j = 0; j < HDD; j++) s += (double)r[j] * (double)r[j];
  c2[i] = (float)s;
}

// ---------------- GEMM1: Q,V = x * W^T (bf16 MFMA), scatter epilogue ----------------
__global__ __launch_bounds__(256) void gemm_qv(
    const unsigned short* __restrict__ xb, const unsigned short* __restrict__ wb,
    unsigned short* __restrict__ qb, unsigned short* __restrict__ vt) {
  __shared__ __align__(16) unsigned short As[128 * 32];
  __shared__ __align__(16) unsigned short Bs[128 * 32];
  int tid = threadIdx.x;
  int wave = tid >> 6, lane = tid & 63;
  int quad = lane >> 4, col = lane & 15;
  int m0 = blockIdx.y * 128;
  int n0 = blockIdx.x * 128 + (blockIdx.x >= 8 ? 1024 : 0);
  f32x4 acc[4][4] = {};
  int row_in = (wave << 4) + (lane >> 2);
  int seg = lane & 3;
  const unsigned short* gA0 = xb + (long)(m0 + row_in) * DD + seg * 8;
  const unsigned short* gA1 = xb + (long)(m0 + 64 + row_in) * DD + seg * 8;
  const unsigned short* gB0 = wb + (long)(n0 + row_in) * DD + seg * 8;
  const unsigned short* gB1 = wb + (long)(n0 + 64 + row_in) * DD + seg * 8;
  unsigned short* lA0 = As + wave * 512;
  unsigned short* lA1 = As + 2048 + wave * 512;
  unsigned short* lB0 = Bs + wave * 512;
  unsigned short* lB1 = Bs + 2048 + wave * 512;
  int wm = wave & 1, wn = wave >> 1;
  const unsigned short* pa = As + (wm * 64 + col) * 32 + quad * 8;
  const unsigned short* pb = Bs + (wn * 64 + col) * 32 + quad * 8;
  for (int kk = 0; kk < DD; kk += 32) {
    __syncthreads();
    load_lds16(gA0 + kk, lA0);
    load_lds16(gA1 + kk, lA1);
    load_lds16(gB0 + kk, lB0);
    load_lds16(gB1 + kk, lB1);
    __syncthreads();
    bf16x8 af[4], bfr[4];
    for (int t = 0; t < 4; t++) af[t]  = *(const bf16x8*)(pa + t * 512);
    for (int t = 0; t < 4; t++) bfr[t] = *(const bf16x8*)(pb + t * 512);
    for (int mt = 0; mt < 4; mt++)
      for (int nt = 0; nt < 4; nt++)
        acc[mt][nt] = __builtin_amdgcn_mfma_f32_16x16x32_bf16(af[mt], bfr[nt], acc[mt][nt], 0, 0, 0);
  }
  for (int mt = 0; mt < 4; mt++)
    for (int nt = 0; nt < 4; nt++) {
      int mbase = m0 + wm * 64 + mt * 16 + quad * 4;
      int n = n0 + wn * 64 + nt * 16 + col;
      int which = n >> 10, e = n & 1023;
      int h = e >> 6, hd = e & 63;
      for (int r = 0; r < 4; r++) {
        int m = mbase + r;
        int b = m >> 11, l = m & 2047;
        unsigned short val = f2bf(acc[mt][nt][r]);
        long bh = (long)(b * HH + h);
        if (which == 0)      qb[(bh * LL + l) * HDD + hd] = val;
        else                 vt[(bh * HDD + hd) * LL + l] = val;
      }
    }
}

// ---------------- K-GEMM: kf = x * Wk^T via split-bf16 3-pass MFMA (fp32 out) ----------------
__global__ __launch_bounds__(256) void kgemm_split(
    const unsigned short* __restrict__ xb, const unsigned short* __restrict__ xl,
    const unsigned short* __restrict__ wb, const unsigned short* __restrict__ wkl,
    float* __restrict__ kf) {
  __shared__ __align__(16) unsigned short Ah[128 * 32];
  __shared__ __align__(16) unsigned short Al[128 * 32];
  __shared__ __align__(16) unsigned short Bh[64 * 32];
  __shared__ __align__(16) unsigned short Bl[64 * 32];
  int tid = threadIdx.x;
  int wave = tid >> 6, lane = tid & 63;
  int quad = lane >> 4, col = lane & 15;
  int n0 = blockIdx.x * 64;   // head h = blockIdx.x
  int m0 = blockIdx.y * 128;
  f32x4 acc[4][2] = {};
  int row_in = (wave << 4) + (lane >> 2);
  int seg = lane & 3;
  const unsigned short* gAh0 = xb + (long)(m0 + row_in) * DD + seg * 8;
  const unsigned short* gAh1 = xb + (long)(m0 + 64 + row_in) * DD + seg * 8;
  const unsigned short* gAl0 = xl + (long)(m0 + row_in) * DD + seg * 8;
  const unsigned short* gAl1 = xl + (long)(m0 + 64 + row_in) * DD + seg * 8;
  const unsigned short* gBh  = wb + (long)(1048576 + (long)(n0 + row_in) * DD) + seg * 8;  // wk block
  const unsigned short* gBl  = wkl + (long)(n0 + row_in) * DD + seg * 8;
  unsigned short* lAh0 = Ah + wave * 512;
  unsigned short* lAh1 = Ah + 2048 + wave * 512;
  unsigned short* lAl0 = Al + wave * 512;
  unsigned short* lAl1 = Al + 2048 + wave * 512;
  unsigned short* lBh  = Bh + wave * 512;
  unsigned short* lBl  = Bl + wave * 512;
  int wm = wave & 1, wn = wave >> 1;
  const unsigned short* pah = Ah + (wm * 64 + col) * 32 + quad * 8;
  const unsigned short* pal = Al + (wm * 64 + col) * 32 + quad * 8;
  const unsigned short* pbh = Bh + (wn * 32 + col) * 32 + quad * 8;
  const unsigned short* pbl = Bl + (wn * 32 + col) * 32 + quad * 8;
  for (int kk = 0; kk < DD; kk += 32) {
    __syncthreads();
    load_lds16(gAh0 + kk, lAh0);
    load_lds16(gAh1 + kk, lAh1);
    load_lds16(gAl0 + kk, lAl0);
    load_lds16(gAl1 + kk, lAl1);
    load_lds16(gBh + kk, lBh);
    load_lds16(gBl + kk, lBl);
    __syncthreads();
    bf16x8 ah[4], al[4], bhf[2], blf[2];
    for (int t = 0; t < 4; t++) ah[t] = *(const bf16x8*)(pah + t * 512);
    for (int t = 0; t < 4; t++) al[t] = *(const bf16x8*)(pal + t * 512);
    for (int t = 0; t < 2; t++) bhf[t] = *(const bf16x8*)(pbh + t * 512);
    for (int t = 0; t < 2; t++) blf[t] = *(const bf16x8*)(pbl + t * 512);
    for (int mt = 0; mt < 4; mt++)
      for (int nt = 0; nt < 2; nt++) {
        acc[mt][nt] = __builtin_amdgcn_mfma_f32_16x16x32_bf16(ah[mt], bhf[nt], acc[mt][nt], 0, 0, 0);
        acc[mt][nt] = __builtin_amdgcn_mfma_f32_16x16x32_bf16(ah[mt], blf[nt], acc[mt][nt], 0, 0, 0);
        acc[mt][nt] = __builtin_amdgcn_mfma_f32_16x16x32_bf16(al[mt], bhf[nt], acc[mt][nt], 0, 0, 0);
      }
  }
  int h = blockIdx.x;
  for (int mt = 0; mt < 4; mt++)
    for (int nt = 0; nt < 2; nt++) {
      int mbase = m0 + wm * 64 + mt * 16 + quad * 4;
      int hd = wn * 32 + nt * 16 + col;
      for (int r = 0; r < 4; r++) {
        int m = mbase + r;
        int b = m >> 11, l = m & 2047;
        kf[((long)(b * HH + h) * LL + l) * HDD + hd] = acc[mt][nt][r];
      }
    }
}

// ---------------- VQ v3: 32 rows/wave (2 rowgroups), LDS codebook dbuf, c2 in LDS ----------------
__global__ __launch_bounds__(256) void vq_mfma(
    const float* __restrict__ kf, const float* __restrict__ cb,
    const float* __restrict__ c2, const unsigned short* __restrict__ cbb,
    const unsigned short* __restrict__ cbl,
    unsigned short* __restrict__ khat, float* __restrict__ scodes,
    float* __restrict__ lsum) {
  __shared__ __align__(16) unsigned short CbH[2][32 * 72];  // 2x4608 B
  __shared__ __align__(16) unsigned short CbL[2][32 * 72];  // 2x4608 B
  __shared__ __align__(16) float Cs[NC];
  __shared__ int finalIdx[128];
  int tid = threadIdx.x, wave = tid >> 6, lane = tid & 63;
  int quad = lane >> 4, col = lane & 15;
  int rb = blockIdx.x;           // 0..15
  int bh = blockIdx.y;
  int h = bh & 15;
  int rbase = rb * 128 + wave * 32;
  const float* c2h = c2 + h * NC;
  Cs[tid] = c2h[tid];
  Cs[tid + 256] = c2h[tid + 256];

  // build B fragments + exact k2 for 2 rowgroups (rows rbase + g*16 + col)
  bf16x8 bhf[2][2], blf[2][2];
  float k2g[2];
#pragma unroll
  for (int g = 0; g < 2; g++) {
    const float* kp = kf + ((long)bh * LL + rbase + g * 16 + col) * HDD + quad * 8;
    float4 t0 = *(const float4*)(kp);
    float4 t1 = *(const float4*)(kp + 4);
    float4 t2 = *(const float4*)(kp + 32);
    float4 t3 = *(const float4*)(kp + 36);
    float fv[16];
    fv[0]=t0.x; fv[1]=t0.y; fv[2]=t0.z; fv[3]=t0.w;
    fv[4]=t1.x; fv[5]=t1.y; fv[6]=t1.z; fv[7]=t1.w;
    fv[8]=t2.x; fv[9]=t2.y; fv[10]=t2.z; fv[11]=t2.w;
    fv[12]=t3.x; fv[13]=t3.y; fv[14]=t3.z; fv[15]=t3.w;
    float k2 = 0.f;
#pragma unroll
    for (int j = 0; j < 16; j++) k2 = fmaf(fv[j], fv[j], k2);
    k2 += __shfl_xor(k2, 16);
    k2 += __shfl_xor(k2, 32);
    k2g[g] = k2;
    u16x8 h0, h1, l0, l1;
#pragma unroll
    for (int j = 0; j < 8; j++) {
      unsigned short hi = f2bf(fv[j]);
      h0[j] = hi; l0[j] = f2bf(fv[j] - bf2f(hi));
      unsigned short hi2 = f2bf(fv[8 + j]);
      h1[j] = hi2; l1[j] = f2bf(fv[8 + j] - bf2f(hi2));
    }
    bhf[g][0] = __builtin_bit_cast(bf16x8, h0);
    bhf[g][1] = __builtin_bit_cast(bf16x8, h1);
    blf[g][0] = __builtin_bit_cast(bf16x8, l0);
    blf[g][1] = __builtin_bit_cast(bf16x8, l1);
  }
  const unsigned short* cbbh = cbb + (long)h * NC * HDD;
  const unsigned short* cblh = cbl + (long)h * NC * HDD;

  // staging role: thread t covers code-row srow (0..31), 8 shorts at sseg
  int srow = tid >> 3;
  int sseg = (tid & 7) * 8;
  const unsigned short* gH = cbbh + (long)srow * HDD + sseg;
  const unsigned short* gL = cblh + (long)srow * HDD + sseg;
  int ldsOff = srow * 72 + sseg;

  {
    u16x8 ph = *(const u16x8*)(gH);
    u16x8 pl = *(const u16x8*)(gL);
    *(u16x8*)(CbH[0] + ldsOff) = ph;
    *(u16x8*)(CbL[0] + ldsOff) = pl;
  }
  __syncthreads();

  float b1v[2] = {1e38f, 1e38f}, b2v[2] = {1e38f, 1e38f};
  int b1i[2] = {0x7fffffff, 0x7fffffff}, b2i[2] = {0x7fffffff, 0x7fffffff};
  for (int t = 0; t < 16; t++) {
    int cur = t & 1;
    u16x8 nh, nl;
    if (t < 15) {
      nh = *(const u16x8*)(gH + (t + 1) * 32 * HDD);
      nl = *(const u16x8*)(gL + (t + 1) * 32 * HDD);
    }
#pragma unroll
    for (int s = 0; s < 2; s++) {
      const unsigned short* rp = CbH[cur] + (s * 16 + col) * 72 + quad * 8;
      const unsigned short* rq = CbL[cur] + (s * 16 + col) * 72 + quad * 8;
      bf16x8 ah0 = *(const bf16x8*)(rp);
      bf16x8 ah1 = *(const bf16x8*)(rp + 32);
      bf16x8 al0 = *(const bf16x8*)(rq);
      bf16x8 al1 = *(const bf16x8*)(rq + 32);
      f32x4 aP0 = {}, aQ0 = {}, aP1 = {}, aQ1 = {};
      aP0 = __builtin_amdgcn_mfma_f32_16x16x32_bf16(ah0, bhf[0][0], aP0, 0, 0, 0);
      aQ0 = __builtin_amdgcn_mfma_f32_16x16x32_bf16(ah1, bhf[0][1], aQ0, 0, 0, 0);
      aP1 = __builtin_amdgcn_mfma_f32_16x16x32_bf16(ah0, bhf[1][0], aP1, 0, 0, 0);
      aQ1 = __builtin_amdgcn_mfma_f32_16x16x32_bf16(ah1, bhf[1][1], aQ1, 0, 0, 0);
      aP0 = __builtin_amdgcn_mfma_f32_16x16x32_bf16(al0, bhf[0][0], aP0, 0, 0, 0);
      aQ0 = __builtin_amdgcn_mfma_f32_16x16x32_bf16(al1, bhf[0][1], aQ0, 0, 0, 0);
      aP1 = __builtin_amdgcn_mfma_f32_16x16x32_bf16(al0, bhf[1][0], aP1, 0, 0, 0);
      aQ1 = __builtin_amdgcn_mfma_f32_16x16x32_bf16(al1, bhf[1][1], aQ1, 0, 0, 0);
      aP0 = __builtin_amdgcn_mfma_f32_16x16x32_bf16(ah0, blf[0][0], aP0, 0, 0, 0);
      aQ0 = __builtin_amdgcn_mfma_f32_16x16x32_bf16(ah1, blf[0][1], aQ0, 0, 0, 0);
      aP1 = __builtin_amdgcn_mfma_f32_16x16x32_bf16(ah0, blf[1][0], aP1, 0, 0, 0);
      aQ1 = __builtin_amdgcn_mfma_f32_16x16x32_bf16(ah1, blf[1][1], aQ1, 0, 0, 0);
      f32x4 c2v = *(const f32x4*)(Cs + t * 32 + s * 16 + quad * 4);
#pragma unroll
      for (int r = 0; r < 4; r++) {
        int idx = t * 32 + s * 16 + quad * 4 + r;
        float v0 = c2v[r] - 2.0f * (aP0[r] + aQ0[r]);
        if (v0 < b1v[0]) { b2v[0] = b1v[0]; b2i[0] = b1i[0]; b1v[0] = v0; b1i[0] = idx; }
        else if (v0 < b2v[0]) { b2v[0] = v0; b2i[0] = idx; }
        float v1 = c2v[r] - 2.0f * (aP1[r] + aQ1[r]);
        if (v1 < b1v[1]) { b2v[1] = b1v[1]; b2i[1] = b1i[1]; b1v[1] = v1; b1i[1] = idx; }
        else if (v1 < b2v[1]) { b2v[1] = v1; b2i[1] = idx; }
      }
    }
    if (t < 15) {
      *(u16x8*)(CbH[cur ^ 1] + ldsOff) = nh;
      *(u16x8*)(CbL[cur ^ 1] + ldsOff) = nl;
    }
    __syncthreads();
  }
  const float DMARG = 0.015625f;
  float partT = 0.f;
#pragma unroll
  for (int g = 0; g < 2; g++) {
    float v1 = b1v[g], v2 = b2v[g];
    int i1 = b1i[g], i2 = b2i[g];
#pragma unroll
    for (int d = 16; d <= 32; d <<= 1) {
      float o1v = __shfl_xor(v1, d); int o1i = __shfl_xor(i1, d);
      float o2v = __shfl_xor(v2, d); int o2i = __shfl_xor(i2, d);
      if (o1v < v1 || (o1v == v1 && o1i < i1)) {
        float nv; int ni;
        if (v1 < o2v || (v1 == o2v && i1 < o2i)) { nv = v1; ni = i1; }
        else { nv = o2v; ni = o2i; }
        v1 = o1v; i1 = o1i; v2 = nv; i2 = ni;
      } else {
        if (o1v < v2 || (o1v == v2 && o1i < i2)) { v2 = o1v; i2 = o1i; }
      }
    }
    // all 4 quad-lanes of row=col hold identical merged (v1,i1,v2,i2)
    bool trig = (v2 - v1 <= DMARG);
    float part;
    int widx = i1;
    if (__any(trig)) {
      const float* kpr = kf + ((long)bh * LL + rbase + g * 16 + col) * HDD + quad * 8;
      float4 f0 = *(const float4*)(kpr);
      float4 f1 = *(const float4*)(kpr + 4);
      float4 f2 = *(const float4*)(kpr + 32);
      float4 f3 = *(const float4*)(kpr + 36);
      const float* c1p = cb + ((long)h * NC + i1) * HDD + quad * 8;
      const float* c2p = cb + ((long)h * NC + i2) * HDD + quad * 8;
      float4 a0 = *(const float4*)(c1p);
      float4 a1 = *(const float4*)(c1p + 4);
      float4 a2 = *(const float4*)(c1p + 32);
      float4 a3 = *(const float4*)(c1p + 36);
      float4 e0 = *(const float4*)(c2p);
      float4 e1 = *(const float4*)(c2p + 4);
      float4 e2 = *(const float4*)(c2p + 32);
      float4 e3 = *(const float4*)(c2p + 36);
      float s1 = 0.f, s2 = 0.f;
#pragma unroll
      for (int j = 0; j < 4; j++) {
        float d;
        d = ((const float*)&f0)[j] - ((const float*)&a0)[j]; s1 = fmaf(d, d, s1);
        d = ((const float*)&f1)[j] - ((const float*)&a1)[j]; s1 = fmaf(d, d, s1);
        d = ((const float*)&f2)[j] - ((const float*)&a2)[j]; s1 = fmaf(d, d, s1);
        d = ((const float*)&f3)[j] - ((const float*)&a3)[j]; s1 = fmaf(d, d, s1);
        d = ((const float*)&f0)[j] - ((const float*)&e0)[j]; s2 = fmaf(d, d, s2);
        d = ((const float*)&f1)[j] - ((const float*)&e1)[j]; s2 = fmaf(d, d, s2);
        d = ((const float*)&f2)[j] - ((const float*)&e2)[j]; s2 = fmaf(d, d, s2);
        d = ((const float*)&f3)[j] - ((const float*)&e3)[j]; s2 = fmaf(d, d, s2);
      }
      s1 += __shfl_xor(s1, 16); s1 += __shfl_xor(s1, 32);
      s2 += __shfl_xor(s2, 16); s2 += __shfl_xor(s2, 32);
      if (trig) {
        if (s2 < s1 || (s2 == s1 && i2 < i1)) { widx = i2; part = s2; }
        else { widx = i1; part = s1; }
      } else {
        part = k2g[g] + v1;
      }
    } else {
      part = k2g[g] + v1;
    }
    if (quad == 0) partT += part;
    if (lane < 16) {
      int row_local = wave * 32 + g * 16 + lane;
      scodes[(long)bh * LL + rb * 128 + row_local] = (float)widx;
      finalIdx[row_local] = widx;
    }
  }
  partT += __shfl_xor(partT, 1);  partT += __shfl_xor(partT, 2);
  partT += __shfl_xor(partT, 4);  partT += __shfl_xor(partT, 8);
  partT += __shfl_xor(partT, 16); partT += __shfl_xor(partT, 32);
  if (lane == 0) atomicAdd(lsum, partT);
  __syncthreads();
  {
    int r = tid >> 1, p = (tid & 1) * 32;
    int code = finalIdx[r];
    const unsigned short* src = cbb + ((long)h * NC + code) * HDD + p;
    unsigned short* dst = khat + ((long)bh * LL + rb * 128 + r) * HDD + p;
    *(u16x8*)(dst)      = *(const u16x8*)(src);
    *(u16x8*)(dst + 8)  = *(const u16x8*)(src + 8);
    *(u16x8*)(dst + 16) = *(const u16x8*)(src + 16);
    *(u16x8*)(dst + 24) = *(const u16x8*)(src + 24);
  }
}

// ---------------- flash attention v2: one q-tile/block, 1024 blocks, reg-prefetch K/V ----------------
// grid (32,32): qt x bh, remapped so 32 qt-blocks of 4 consecutive bh share an XCD.
// Per iteration: prefetch regs for kt+1 issued before compute (T14); 2 barriers.
// Math identical to previous version (same MFMA order, same exp2 softmax, same mask).
__global__ __launch_bounds__(256) void attn_kernel(
    const unsigned short* __restrict__ qb, const unsigned short* __restrict__ khat,
    const unsigned short* __restrict__ vt, unsigned short* __restrict__ attnb) {
  __shared__ __align__(16) unsigned short Kbuf[64 * 72];   // 9216 B (pad 72)
  __shared__ __align__(16) unsigned short Vbuf[64 * 72];   // 9216 B
  __shared__ __align__(16) unsigned short Pbuf[4][16 * 72];// 9216 B
  int tid = threadIdx.x, wave = tid >> 6, lane = tid & 63;
  int quad = lane >> 4, col = lane & 15;
  // XCD-aware remap (bijective: 1024 = 8 XCD x 128)
  int id = blockIdx.y * 32 + blockIdx.x;
  int xcd = id & 7, idx = id >> 3;
  int bh = xcd * 4 + (idx >> 5);
  int qt = idx & 31;
  int b = bh >> 4, h = bh & 15;
  int qbase = qt * 64 + wave * 16;
  const unsigned short* qr = qb + ((long)bh * LL + qbase + col) * HDD;
  bf16x8 aq0 = *(const bf16x8*)(qr + quad * 8);
  bf16x8 aq1 = *(const bf16x8*)(qr + 32 + quad * 8);
  float l[4] = {0.f, 0.f, 0.f, 0.f};
  f32x4 o[4] = {};
  unsigned short* P = Pbuf[wave];
  const unsigned short* kh = khat + (long)bh * LL * HDD;
  const unsigned short* vh = vt + (long)bh * HDD * LL;
  // staging role: thread t covers row srow (0..63), chunks sc and sc+32
  int srow = tid >> 2, sc = (tid & 3) * 8;
  const unsigned short* gK = kh + (long)srow * HDD + sc;
  const unsigned short* gV = vh + (long)srow * LL + sc;
  unsigned short* lK = Kbuf + srow * 72 + sc;
  unsigned short* lV = Vbuf + srow * 72 + sc;
  const float SCL = 0.18033688011112042f;  // log2(e) / 8
  // prefetch tile 0 into regs
  u16x8 rk0 = *(const u16x8*)(gK);
  u16x8 rk1 = *(const u16x8*)(gK + 32);
  u16x8 rv0 = *(const u16x8*)(gV);
  u16x8 rv1 = *(const u16x8*)(gV + 32);
  for (int kt = 0; kt <= qt; kt++) {
    __syncthreads();   // all waves done reading K/V of previous tile
    *(u16x8*)lK        = rk0;
    *(u16x8*)(lK + 32) = rk1;
    *(u16x8*)lV        = rv0;
    *(u16x8*)(lV + 32) = rv1;
    __syncthreads();
    if (kt < qt) {     // issue next-tile loads early; latency hides under compute
      const unsigned short* nK = gK + (long)(kt + 1) * 64 * HDD;
      const unsigned short* nV = gV + (kt + 1) * 64;
      rk0 = *(const u16x8*)(nK);
      rk1 = *(const u16x8*)(nK + 32);
      rv0 = *(const u16x8*)(nV);
      rv1 = *(const u16x8*)(nV + 32);
    }
    int kbase = kt * 64;
    f32x4 z[4];
    for (int nt = 0; nt < 4; nt++) {
      const unsigned short* krow = Kbuf + (nt * 16 + col) * 72;
      bf16x8 k0 = *(const bf16x8*)(krow + quad * 8);
      bf16x8 k1 = *(const bf16x8*)(krow + 32 + quad * 8);
      f32x4 zz = {};
      zz = __builtin_amdgcn_mfma_f32_16x16x32_bf16(aq0, k0, zz, 0, 0, 0);
      zz = __builtin_amdgcn_mfma_f32_16x16x32_bf16(aq1, k1, zz, 0, 0, 0);
      z[nt] = zz;
    }
    for (int nt = 0; nt < 4; nt++) {
      int key = kbase + nt * 16 + col;
      for (int r = 0; r < 4; r++) {
        float sc2 = z[nt][r] * SCL;
        if (kt == qt && key > qbase + quad * 4 + r) sc2 = -1e30f;
        float p = exp2f(sc2);
        l[r] += p;
        P[(quad * 4 + r) * 72 + nt * 16 + col] = __builtin_bit_cast(unsigned short, (__bf16)p);
      }
    }
    bf16x8 ap0 = *(const bf16x8*)(P + col * 72 + quad * 8);
    bf16x8 ap1 = *(const bf16x8*)(P + col * 72 + 32 + quad * 8);
    for (int nt = 0; nt < 4; nt++) {
      const unsigned short* vrow = Vbuf + (nt * 16 + col) * 72;
      bf16x8 v0 = *(const bf16x8*)(vrow + quad * 8);
      bf16x8 v1 = *(const bf16x8*)(vrow + 32 + quad * 8);
      o[nt] = __builtin_amdgcn_mfma_f32_16x16x32_bf16(ap0, v0, o[nt], 0, 0, 0);
      o[nt] = __builtin_amdgcn_mfma_f32_16x16x32_bf16(ap1, v1, o[nt], 0, 0, 0);
    }
  }
  float inv[4];
  for (int r = 0; r < 4; r++) {
    float t = l[r];
    t += __shfl_xor(t, 1); t += __shfl_xor(t, 2);
    t += __shfl_xor(t, 4); t += __shfl_xor(t, 8);
    inv[r] = 1.0f / t;
  }
  for (int r = 0; r < 4; r++) {
    int row = qbase + quad * 4 + r;
    for (int nt = 0; nt < 4; nt++) {
      int hd = nt * 16 + col;
      attnb[((long)b * LL + row) * DD + h * HDD + hd] = f2bf(o[nt][r] * inv[r]);
    }
  }
}

// ---------------- GEMM2: out = attn * Wo^T (fp32 store) ----------------
__global__ __launch_bounds__(256) void gemm_out(
    const unsigned short* __restrict__ attnb, const unsigned short* __restrict__ wob,
    float* __restrict__ out) {
  __shared__ __align__(16) unsigned short As[128 * 32];
  __shared__ __align__(16) unsigned short Bs[128 * 32];
  int tid = threadIdx.x;
  int wave = tid >> 6, lane = tid & 63;
  int quad = lane >> 4, col = lane & 15;
  int m0 = blockIdx.y * 128;
  int n0 = blockIdx.x * 128;
  f32x4 acc[4][4] = {};
  int row_in = (wave << 4) + (lane >> 2);
  int seg = lane & 3;
  const unsigned short* gA0 = attnb + (long)(m0 + row_in) * DD + seg * 8;
  const unsigned short* gA1 = attnb + (long)(m0 + 64 + row_in) * DD + seg * 8;
  const unsigned short* gB0 = wob + (long)(n0 + row_in) * DD + seg * 8;
  const unsigned short* gB1 = wob + (long)(n0 + 64 + row_in) * DD + seg * 8;
  unsigned short* lA0 = As + wave * 512;
  unsigned short* lA1 = As + 2048 + wave * 512;
  unsigned short* lB0 = Bs + wave * 512;
  unsigned short* lB1 = Bs + 2048 + wave * 512;
  int wm = wave & 1, wn = wave >> 1;
  const unsigned short* pa = As + (wm * 64 + col) * 32 + quad * 8;
  const unsigned short* pb = Bs + (wn * 64 + col) * 32 + quad * 8;
  for (int kk = 0; kk < DD; kk += 32) {
    __syncthreads();
    load_lds16(gA0 + kk, lA0);
    load_lds16(gA1 + kk, lA1);
    load_lds16(gB0 + kk, lB0);
    load_lds16(gB1 + kk, lB1);
    __syncthreads();
    bf16x8 af[4], bfr[4];
    for (int t = 0; t < 4; t++) af[t]  = *(const bf16x8*)(pa + t * 512);
    for (int t = 0; t < 4; t++) bfr[t] = *(const bf16x8*)(pb + t * 512);
    for (int mt = 0; mt < 4; mt++)
      for (int nt = 0; nt < 4; nt++)
        acc[mt][nt] = __builtin_amdgcn_mfma_f32_16x16x32_bf16(af[mt], bfr[nt], acc[mt][nt], 0, 0, 0);
  }
  for (int mt = 0; mt < 4; mt++)
    for (int nt = 0; nt < 4; nt++) {
      int mbase = m0 + wm * 64 + mt * 16 + quad * 4;
      int n = n0 + wn * 64 + nt * 16 + col;
      for (int r = 0; r < 4; r++)
        out[(long)(mbase + r) * DD + n] = acc[mt][nt][r];
    }
}

// ---------------- finalize scalars ----------------
__global__ void finalize(const float* __restrict__ lsum, float* __restrict__ out) {
  if (threadIdx.x == 0) {
    float v = lsum[0] / (float)(BB * HH * LL);
    out[4194304] = v;
    out[4194305] = v;
  }
}

extern "C" void kernel_launch(void* const* d_in, const int* in_sizes, int n_in,
                              void* d_out, int out_size, void* d_ws, size_t ws_size,
                              hipStream_t stream) {
  const float* x  = (const float*)d_in[0];
  const float* wq = (const float*)d_in[1];
  const float* wk = (const float*)d_in[2];
  const float* wv = (const float*)d_in[3];
  const float* wo = (const float*)d_in[4];
  const float* cb = (const float*)d_in[5];
  float* out = (float*)d_out;

  char* ws = (char*)d_ws;
  size_t off = 0;
  auto alloc = [&](size_t bytes) {
    void* p = ws + off;
    off = (off + bytes + 255) & ~(size_t)255;
    return p;
  };
  unsigned short* xb    = (unsigned short*)alloc(4194304 * 2);
  unsigned short* xl    = (unsigned short*)alloc(4194304 * 2);
  unsigned short* wb    = (unsigned short*)alloc(3145728 * 2);
  unsigned short* wkl   = (unsigned short*)alloc(1048576 * 2);
  unsigned short* wob   = (unsigned short*)alloc(1048576 * 2);
  unsigned short* cbb   = (unsigned short*)alloc(524288 * 2);
  unsigned short* cbl   = (unsigned short*)alloc(524288 * 2);
  unsigned short* qb    = (unsigned short*)alloc(4194304 * 2);
  unsigned short* vt    = (unsigned short*)alloc(4194304 * 2);
  unsigned short* khat  = (unsigned short*)alloc(4194304 * 2);
  unsigned short* attnb = (unsigned short*)alloc(4194304 * 2);
  float* kf   = (float*)alloc(4194304 * 4);
  float* c2   = (float*)alloc(8192 * 4);
  float* lsum = (float*)alloc(256);

  cast_all<<<dim3(4096), dim3(256), 0, stream>>>(x, wq, wk, wv, wo, cb, xb, xl, wb, wkl, wob, cbb, cbl, lsum);
  c2_kernel<<<dim3(32), dim3(256), 0, stream>>>(cb, c2);
  gemm_qv<<<dim3(16, 32), dim3(256), 0, stream>>>(xb, wb, qb, vt);
  kgemm_split<<<dim3(16, 32), dim3(256), 0, stream>>>(xb, xl, wb, wkl, kf);
  vq_mfma<<<dim3(16, 32), dim3(256), 0, stream>>>(kf, cb, c2, cbb, cbl, khat, out + 4194306, lsum);
  attn_kernel<<<dim3(32, 32), dim3(256), 0, stream>>>(qb, khat, vt, attnb);
  gemm_out<<<dim3(8, 32), dim3(256), 0, stream>>>(attnb, wob, out);
  finalize<<<dim3(1), dim3(64), 0, stream>>>(lsum, out);
}

// Round 5
// 300.289 us; speedup vs baseline: 1.0804x; 1.0804x over previous
//
#include <hip/hip_runtime.h>
#include <stdint.h>

#define BB 2
#define HH 16
#define LL 2048
#define DD 1024
#define HDD 64
#define NC 512

typedef __bf16 bf16x8 __attribute__((ext_vector_type(8)));
typedef float f32x4 __attribute__((ext_vector_type(4)));
typedef unsigned short u16x8 __attribute__((ext_vector_type(8)));

__device__ __forceinline__ unsigned short f2bf(float f) {
  union { float f; unsigned u; } v; v.f = f;
  unsigned u = v.u;
  u += 0x7fffu + ((u >> 16) & 1u);
  return (unsigned short)(u >> 16);
}
__device__ __forceinline__ float bf2f(unsigned short h) {
  union { unsigned u; float f; } v; v.u = ((unsigned)h) << 16;
  return v.f;
}

// async global->LDS, 16B per lane; lds ptr must be wave-uniform base (HW adds lane*16)
__device__ __forceinline__ void load_lds16(const unsigned short* g, unsigned short* l) {
  __builtin_amdgcn_global_load_lds((const __attribute__((address_space(1))) void*)g,
                                   (__attribute__((address_space(3))) void*)l, 16, 0, 0);
}

// ---------------- cast kernel ----------------
__global__ void cast_all(const float* __restrict__ x, const float* __restrict__ wq,
                         const float* __restrict__ wk, const float* __restrict__ wv,
                         const float* __restrict__ wo, const float* __restrict__ cb,
                         unsigned short* __restrict__ xb, unsigned short* __restrict__ xl,
                         unsigned short* __restrict__ wb, unsigned short* __restrict__ wkl,
                         unsigned short* __restrict__ wob, unsigned short* __restrict__ cbb,
                         unsigned short* __restrict__ cbl, float* __restrict__ lsum) {
  long i = (long)blockIdx.x * blockDim.x + threadIdx.x;
  if (i == 0) lsum[0] = 0.f;
  const long NX = 4194304, NW = 1048576, NCB = 524288;
  const long TOT = NX + 4 * NW + NCB;
  for (long t = i; t < TOT; t += (long)gridDim.x * blockDim.x) {
    if (t < NX) {
      float v = x[t];
      unsigned short hi = f2bf(v);
      xb[t] = hi;
      xl[t] = f2bf(v - bf2f(hi));
    } else if (t < NX + NW) {
      wb[t - NX] = f2bf(wq[t - NX]);
    } else if (t < NX + 2 * NW) {
      long idx = t - NX - NW;
      float v = wk[idx];
      unsigned short hi = f2bf(v);
      wb[NW + idx] = hi;
      wkl[idx] = f2bf(v - bf2f(hi));
    } else if (t < NX + 3 * NW) {
      wb[t - NX] = f2bf(wv[t - NX - 2 * NW]);
    } else if (t < NX + 4 * NW) {
      wob[t - NX - 3 * NW] = f2bf(wo[t - NX - 3 * NW]);
    } else {
      long idx = t - NX - 4 * NW;
      float v = cb[idx];
      unsigned short hi = f2bf(v);
      cbb[idx] = hi;
      cbl[idx] = f2bf(v - bf2f(hi));
    }
  }
}

// ---------------- codebook norms (fp64 accumulate) ----------------
__global__ void c2_kernel(const float* __restrict__ cb, float* __restrict__ c2) {
  int i = blockIdx.x * blockDim.x + threadIdx.x;
  if (i >= HH * NC) return;
  const float* r = cb + (long)i * HDD;
  double s = 0.0;
  for (int j = 0; j < HDD; j++) s += (double)r[j] * (double)r[j];
  c2[i] = (float)s;
}

// ---------------- GEMM1: Q,V = x * W^T (bf16 MFMA), scatter epilogue ----------------
__global__ __launch_bounds__(256) void gemm_qv(
    const unsigned short* __restrict__ xb, const unsigned short* __restrict__ wb,
    unsigned short* __restrict__ qb, unsigned short* __restrict__ vt) {
  __shared__ __align__(16) unsigned short As[128 * 32];
  __shared__ __align__(16) unsigned short Bs[128 * 32];
  int tid = threadIdx.x;
  int wave = tid >> 6, lane = tid & 63;
  int quad = lane >> 4, col = lane & 15;
  int m0 = blockIdx.y * 128;
  int n0 = blockIdx.x * 128 + (blockIdx.x >= 8 ? 1024 : 0);
  f32x4 acc[4][4] = {};
  int row_in = (wave << 4) + (lane >> 2);
  int seg = lane & 3;
  const unsigned short* gA0 = xb + (long)(m0 + row_in) * DD + seg * 8;
  const unsigned short* gA1 = xb + (long)(m0 + 64 + row_in) * DD + seg * 8;
  const unsigned short* gB0 = wb + (long)(n0 + row_in) * DD + seg * 8;
  const unsigned short* gB1 = wb + (long)(n0 + 64 + row_in) * DD + seg * 8;
  unsigned short* lA0 = As + wave * 512;
  unsigned short* lA1 = As + 2048 + wave * 512;
  unsigned short* lB0 = Bs + wave * 512;
  unsigned short* lB1 = Bs + 2048 + wave * 512;
  int wm = wave & 1, wn = wave >> 1;
  const unsigned short* pa = As + (wm * 64 + col) * 32 + quad * 8;
  const unsigned short* pb = Bs + (wn * 64 + col) * 32 + quad * 8;
  for (int kk = 0; kk < DD; kk += 32) {
    __syncthreads();
    load_lds16(gA0 + kk, lA0);
    load_lds16(gA1 + kk, lA1);
    load_lds16(gB0 + kk, lB0);
    load_lds16(gB1 + kk, lB1);
    __syncthreads();
    bf16x8 af[4], bfr[4];
    for (int t = 0; t < 4; t++) af[t]  = *(const bf16x8*)(pa + t * 512);
    for (int t = 0; t < 4; t++) bfr[t] = *(const bf16x8*)(pb + t * 512);
    for (int mt = 0; mt < 4; mt++)
      for (int nt = 0; nt < 4; nt++)
        acc[mt][nt] = __builtin_amdgcn_mfma_f32_16x16x32_bf16(af[mt], bfr[nt], acc[mt][nt], 0, 0, 0);
  }
  for (int mt = 0; mt < 4; mt++)
    for (int nt = 0; nt < 4; nt++) {
      int mbase = m0 + wm * 64 + mt * 16 + quad * 4;
      int n = n0 + wn * 64 + nt * 16 + col;
      int which = n >> 10, e = n & 1023;
      int h = e >> 6, hd = e & 63;
      for (int r = 0; r < 4; r++) {
        int m = mbase + r;
        int b = m >> 11, l = m & 2047;
        unsigned short val = f2bf(acc[mt][nt][r]);
        long bh = (long)(b * HH + h);
        if (which == 0)      qb[(bh * LL + l) * HDD + hd] = val;
        else                 vt[(bh * HDD + hd) * LL + l] = val;
      }
    }
}

// ---------------- FUSED K-GEMM + VQ: no kf round-trip ----------------
// Phase 1: K-tile = x*Wk^T via split-bf16 3-pass MFMA (identical to kgemm_split).
// Phase 2: acc -> LDS kfL[128][68] fp32 (padded stride, 2-way-free banks).
// Phase 3: VQ v3 rounds (identical math) with B-frags/k2/rescore read from kfL.
// LDS overlay: GEMM bufs [0,24576) live inside kfL region [0,34816) - barrier-separated.
__global__ __launch_bounds__(256) void kvq(
    const unsigned short* __restrict__ xb, const unsigned short* __restrict__ xl,
    const unsigned short* __restrict__ wb, const unsigned short* __restrict__ wkl,
    const float* __restrict__ cb, const float* __restrict__ c2,
    const unsigned short* __restrict__ cbb, const unsigned short* __restrict__ cbl,
    unsigned short* __restrict__ khat, float* __restrict__ scodes,
    float* __restrict__ lsum) {
  __shared__ __align__(16) char smem[55808];
  unsigned short* Ah = (unsigned short*)smem;            // 8192 B
  unsigned short* Al = (unsigned short*)(smem + 8192);   // 8192 B
  unsigned short* Bh = (unsigned short*)(smem + 16384);  // 4096 B
  unsigned short* Bl = (unsigned short*)(smem + 20480);  // 4096 B
  float* kfL = (float*)smem;                             // 34816 B = 128*68*4
  unsigned short* CbHb = (unsigned short*)(smem + 34816);// 2 bufs x 4608 B
  unsigned short* CbLb = (unsigned short*)(smem + 44032);// 2 bufs x 4608 B
  float* Cs = (float*)(smem + 53248);                    // 2048 B
  int* finalIdx = (int*)(smem + 55296);                  // 512 B

  int tid = threadIdx.x;
  int wave = tid >> 6, lane = tid & 63;
  int quad = lane >> 4, col = lane & 15;
  // XCD swizzle: group same-m-tile blocks per XCD (x-tile L2 reuse x16)
  int id = blockIdx.y * 16 + blockIdx.x;   // 512 blocks
  int xcd = id & 7, sidx = id >> 3;        // sidx 0..63
  int mt4 = xcd * 4 + (sidx >> 4);         // m-tile 0..31
  int h = sidx & 15;
  int m0 = mt4 * 128;
  int n0 = h * 64;
  int bgl = m0 >> 11;                      // batch
  int l0 = m0 & 2047;
  long bh = (long)(bgl * HH + h);

  // stage c2 row into LDS (region disjoint from GEMM bufs)
  Cs[tid] = c2[h * NC + tid];
  Cs[tid + 256] = c2[h * NC + 256 + tid];

  // ---------- Phase 1: GEMM ----------
  f32x4 acc[4][2] = {};
  int row_in = (wave << 4) + (lane >> 2);
  int seg = lane & 3;
  const unsigned short* gAh0 = xb + (long)(m0 + row_in) * DD + seg * 8;
  const unsigned short* gAh1 = xb + (long)(m0 + 64 + row_in) * DD + seg * 8;
  const unsigned short* gAl0 = xl + (long)(m0 + row_in) * DD + seg * 8;
  const unsigned short* gAl1 = xl + (long)(m0 + 64 + row_in) * DD + seg * 8;
  const unsigned short* gBh  = wb + (long)(1048576 + (long)(n0 + row_in) * DD) + seg * 8;
  const unsigned short* gBl  = wkl + (long)(n0 + row_in) * DD + seg * 8;
  unsigned short* lAh0 = Ah + wave * 512;
  unsigned short* lAh1 = Ah + 2048 + wave * 512;
  unsigned short* lAl0 = Al + wave * 512;
  unsigned short* lAl1 = Al + 2048 + wave * 512;
  unsigned short* lBh  = Bh + wave * 512;
  unsigned short* lBl  = Bl + wave * 512;
  int wm = wave & 1, wn = wave >> 1;
  const unsigned short* pah = Ah + (wm * 64 + col) * 32 + quad * 8;
  const unsigned short* pal = Al + (wm * 64 + col) * 32 + quad * 8;
  const unsigned short* pbh = Bh + (wn * 32 + col) * 32 + quad * 8;
  const unsigned short* pbl = Bl + (wn * 32 + col) * 32 + quad * 8;
  for (int kk = 0; kk < DD; kk += 32) {
    __syncthreads();
    load_lds16(gAh0 + kk, lAh0);
    load_lds16(gAh1 + kk, lAh1);
    load_lds16(gAl0 + kk, lAl0);
    load_lds16(gAl1 + kk, lAl1);
    load_lds16(gBh + kk, lBh);
    load_lds16(gBl + kk, lBl);
    __syncthreads();
    bf16x8 ah[4], al[4], bhf[2], blf[2];
    for (int t = 0; t < 4; t++) ah[t] = *(const bf16x8*)(pah + t * 512);
    for (int t = 0; t < 4; t++) al[t] = *(const bf16x8*)(pal + t * 512);
    for (int t = 0; t < 2; t++) bhf[t] = *(const bf16x8*)(pbh + t * 512);
    for (int t = 0; t < 2; t++) blf[t] = *(const bf16x8*)(pbl + t * 512);
    for (int mt = 0; mt < 4; mt++)
      for (int nt = 0; nt < 2; nt++) {
        acc[mt][nt] = __builtin_amdgcn_mfma_f32_16x16x32_bf16(ah[mt], bhf[nt], acc[mt][nt], 0, 0, 0);
        acc[mt][nt] = __builtin_amdgcn_mfma_f32_16x16x32_bf16(ah[mt], blf[nt], acc[mt][nt], 0, 0, 0);
        acc[mt][nt] = __builtin_amdgcn_mfma_f32_16x16x32_bf16(al[mt], bhf[nt], acc[mt][nt], 0, 0, 0);
      }
  }
  // ---------- Phase 2: acc -> kfL, and stage codebook tile 0 ----------
  __syncthreads();  // all ds_reads of GEMM bufs done before overwrite
  const unsigned short* cbbh = cbb + (long)h * NC * HDD;
  const unsigned short* cblh = cbl + (long)h * NC * HDD;
  int srow = tid >> 3;
  int sseg = (tid & 7) * 8;
  const unsigned short* gH = cbbh + (long)srow * HDD + sseg;
  const unsigned short* gL = cblh + (long)srow * HDD + sseg;
  int ldsOff = srow * 72 + sseg;
  u16x8 ph0 = *(const u16x8*)(gH);
  u16x8 pl0 = *(const u16x8*)(gL);
  for (int mt = 0; mt < 4; mt++)
    for (int nt = 0; nt < 2; nt++) {
      int rbasew = wm * 64 + mt * 16 + quad * 4;
      int hd = wn * 32 + nt * 16 + col;
      for (int r = 0; r < 4; r++)
        kfL[(rbasew + r) * 68 + hd] = acc[mt][nt][r];
    }
  *(u16x8*)(CbHb + ldsOff) = ph0;
  *(u16x8*)(CbLb + ldsOff) = pl0;
  __syncthreads();

  // ---------- Phase 3: VQ rounds (identical math to vq_mfma v3) ----------
  bf16x8 bfh[2][2], bfl[2][2];
  float k2g[2];
#pragma unroll
  for (int g = 0; g < 2; g++) {
    const float* kp = kfL + (wave * 32 + g * 16 + col) * 68 + quad * 8;
    float4 t0 = *(const float4*)(kp);
    float4 t1 = *(const float4*)(kp + 4);
    float4 t2 = *(const float4*)(kp + 32);
    float4 t3 = *(const float4*)(kp + 36);
    float fv[16];
    fv[0]=t0.x; fv[1]=t0.y; fv[2]=t0.z; fv[3]=t0.w;
    fv[4]=t1.x; fv[5]=t1.y; fv[6]=t1.z; fv[7]=t1.w;
    fv[8]=t2.x; fv[9]=t2.y; fv[10]=t2.z; fv[11]=t2.w;
    fv[12]=t3.x; fv[13]=t3.y; fv[14]=t3.z; fv[15]=t3.w;
    float k2 = 0.f;
#pragma unroll
    for (int j = 0; j < 16; j++) k2 = fmaf(fv[j], fv[j], k2);
    k2 += __shfl_xor(k2, 16);
    k2 += __shfl_xor(k2, 32);
    k2g[g] = k2;
    u16x8 h0, h1, l0u, l1u;
#pragma unroll
    for (int j = 0; j < 8; j++) {
      unsigned short hi = f2bf(fv[j]);
      h0[j] = hi; l0u[j] = f2bf(fv[j] - bf2f(hi));
      unsigned short hi2 = f2bf(fv[8 + j]);
      h1[j] = hi2; l1u[j] = f2bf(fv[8 + j] - bf2f(hi2));
    }
    bfh[g][0] = __builtin_bit_cast(bf16x8, h0);
    bfh[g][1] = __builtin_bit_cast(bf16x8, h1);
    bfl[g][0] = __builtin_bit_cast(bf16x8, l0u);
    bfl[g][1] = __builtin_bit_cast(bf16x8, l1u);
  }
  float b1v[2] = {1e38f, 1e38f}, b2v[2] = {1e38f, 1e38f};
  int b1i[2] = {0x7fffffff, 0x7fffffff}, b2i[2] = {0x7fffffff, 0x7fffffff};
  for (int t = 0; t < 16; t++) {
    int cur = t & 1;
    u16x8 nh, nl;
    if (t < 15) {
      nh = *(const u16x8*)(gH + (t + 1) * 32 * HDD);
      nl = *(const u16x8*)(gL + (t + 1) * 32 * HDD);
    }
    const unsigned short* CbHc = CbHb + cur * 2304;
    const unsigned short* CbLc = CbLb + cur * 2304;
#pragma unroll
    for (int s = 0; s < 2; s++) {
      const unsigned short* rp = CbHc + (s * 16 + col) * 72 + quad * 8;
      const unsigned short* rq = CbLc + (s * 16 + col) * 72 + quad * 8;
      bf16x8 ah0 = *(const bf16x8*)(rp);
      bf16x8 ah1 = *(const bf16x8*)(rp + 32);
      bf16x8 al0 = *(const bf16x8*)(rq);
      bf16x8 al1 = *(const bf16x8*)(rq + 32);
      f32x4 aP0 = {}, aQ0 = {}, aP1 = {}, aQ1 = {};
      aP0 = __builtin_amdgcn_mfma_f32_16x16x32_bf16(ah0, bfh[0][0], aP0, 0, 0, 0);
      aQ0 = __builtin_amdgcn_mfma_f32_16x16x32_bf16(ah1, bfh[0][1], aQ0, 0, 0, 0);
      aP1 = __builtin_amdgcn_mfma_f32_16x16x32_bf16(ah0, bfh[1][0], aP1, 0, 0, 0);
      aQ1 = __builtin_amdgcn_mfma_f32_16x16x32_bf16(ah1, bfh[1][1], aQ1, 0, 0, 0);
      aP0 = __builtin_amdgcn_mfma_f32_16x16x32_bf16(al0, bfh[0][0], aP0, 0, 0, 0);
      aQ0 = __builtin_amdgcn_mfma_f32_16x16x32_bf16(al1, bfh[0][1], aQ0, 0, 0, 0);
      aP1 = __builtin_amdgcn_mfma_f32_16x16x32_bf16(al0, bfh[1][0], aP1, 0, 0, 0);
      aQ1 = __builtin_amdgcn_mfma_f32_16x16x32_bf16(al1, bfh[1][1], aQ1, 0, 0, 0);
      aP0 = __builtin_amdgcn_mfma_f32_16x16x32_bf16(ah0, bfl[0][0], aP0, 0, 0, 0);
      aQ0 = __builtin_amdgcn_mfma_f32_16x16x32_bf16(ah1, bfl[0][1], aQ0, 0, 0, 0);
      aP1 = __builtin_amdgcn_mfma_f32_16x16x32_bf16(ah0, bfl[1][0], aP1, 0, 0, 0);
      aQ1 = __builtin_amdgcn_mfma_f32_16x16x32_bf16(ah1, bfl[1][1], aQ1, 0, 0, 0);
      f32x4 c2v = *(const f32x4*)(Cs + t * 32 + s * 16 + quad * 4);
#pragma unroll
      for (int r = 0; r < 4; r++) {
        int idx = t * 32 + s * 16 + quad * 4 + r;
        float v0 = c2v[r] - 2.0f * (aP0[r] + aQ0[r]);
        if (v0 < b1v[0]) { b2v[0] = b1v[0]; b2i[0] = b1i[0]; b1v[0] = v0; b1i[0] = idx; }
        else if (v0 < b2v[0]) { b2v[0] = v0; b2i[0] = idx; }
        float v1 = c2v[r] - 2.0f * (aP1[r] + aQ1[r]);
        if (v1 < b1v[1]) { b2v[1] = b1v[1]; b2i[1] = b1i[1]; b1v[1] = v1; b1i[1] = idx; }
        else if (v1 < b2v[1]) { b2v[1] = v1; b2i[1] = idx; }
      }
    }
    if (t < 15) {
      *(u16x8*)(CbHb + (cur ^ 1) * 2304 + ldsOff) = nh;
      *(u16x8*)(CbLb + (cur ^ 1) * 2304 + ldsOff) = nl;
    }
    __syncthreads();
  }
  const float DMARG = 0.015625f;
  float partT = 0.f;
#pragma unroll
  for (int g = 0; g < 2; g++) {
    float v1 = b1v[g], v2 = b2v[g];
    int i1 = b1i[g], i2 = b2i[g];
#pragma unroll
    for (int d = 16; d <= 32; d <<= 1) {
      float o1v = __shfl_xor(v1, d); int o1i = __shfl_xor(i1, d);
      float o2v = __shfl_xor(v2, d); int o2i = __shfl_xor(i2, d);
      if (o1v < v1 || (o1v == v1 && o1i < i1)) {
        float nv; int ni;
        if (v1 < o2v || (v1 == o2v && i1 < o2i)) { nv = v1; ni = i1; }
        else { nv = o2v; ni = o2i; }
        v1 = o1v; i1 = o1i; v2 = nv; i2 = ni;
      } else {
        if (o1v < v2 || (o1v == v2 && o1i < i2)) { v2 = o1v; i2 = o1i; }
      }
    }
    bool trig = (v2 - v1 <= DMARG);
    float part;
    int widx = i1;
    if (__any(trig)) {
      const float* kpr = kfL + (wave * 32 + g * 16 + col) * 68 + quad * 8;
      float4 f0 = *(const float4*)(kpr);
      float4 f1 = *(const float4*)(kpr + 4);
      float4 f2 = *(const float4*)(kpr + 32);
      float4 f3 = *(const float4*)(kpr + 36);
      const float* c1p = cb + ((long)h * NC + i1) * HDD + quad * 8;
      const float* c2p = cb + ((long)h * NC + i2) * HDD + quad * 8;
      float4 a0 = *(const float4*)(c1p);
      float4 a1 = *(const float4*)(c1p + 4);
      float4 a2 = *(const float4*)(c1p + 32);
      float4 a3 = *(const float4*)(c1p + 36);
      float4 e0 = *(const float4*)(c2p);
      float4 e1 = *(const float4*)(c2p + 4);
      float4 e2 = *(const float4*)(c2p + 32);
      float4 e3 = *(const float4*)(c2p + 36);
      float s1 = 0.f, s2 = 0.f;
#pragma unroll
      for (int j = 0; j < 4; j++) {
        float d;
        d = ((const float*)&f0)[j] - ((const float*)&a0)[j]; s1 = fmaf(d, d, s1);
        d = ((const float*)&f1)[j] - ((const float*)&a1)[j]; s1 = fmaf(d, d, s1);
        d = ((const float*)&f2)[j] - ((const float*)&a2)[j]; s1 = fmaf(d, d, s1);
        d = ((const float*)&f3)[j] - ((const float*)&a3)[j]; s1 = fmaf(d, d, s1);
        d = ((const float*)&f0)[j] - ((const float*)&e0)[j]; s2 = fmaf(d, d, s2);
        d = ((const float*)&f1)[j] - ((const float*)&e1)[j]; s2 = fmaf(d, d, s2);
        d = ((const float*)&f2)[j] - ((const float*)&e2)[j]; s2 = fmaf(d, d, s2);
        d = ((const float*)&f3)[j] - ((const float*)&e3)[j]; s2 = fmaf(d, d, s2);
      }
      s1 += __shfl_xor(s1, 16); s1 += __shfl_xor(s1, 32);
      s2 += __shfl_xor(s2, 16); s2 += __shfl_xor(s2, 32);
      if (trig) {
        if (s2 < s1 || (s2 == s1 && i2 < i1)) { widx = i2; part = s2; }
        else { widx = i1; part = s1; }
      } else {
        part = k2g[g] + v1;
      }
    } else {
      part = k2g[g] + v1;
    }
    if (quad == 0) partT += part;
    if (lane < 16) {
      int row_local = wave * 32 + g * 16 + lane;
      scodes[bh * LL + l0 + row_local] = (float)widx;
      finalIdx[row_local] = widx;
    }
  }
  partT += __shfl_xor(partT, 1);  partT += __shfl_xor(partT, 2);
  partT += __shfl_xor(partT, 4);  partT += __shfl_xor(partT, 8);
  partT += __shfl_xor(partT, 16); partT += __shfl_xor(partT, 32);
  if (lane == 0) atomicAdd(lsum, partT);
  __syncthreads();
  {
    int r = tid >> 1, p = (tid & 1) * 32;
    int code = finalIdx[r];
    const unsigned short* src = cbb + ((long)h * NC + code) * HDD + p;
    unsigned short* dst = khat + (bh * LL + l0 + r) * HDD + p;
    *(u16x8*)(dst)      = *(const u16x8*)(src);
    *(u16x8*)(dst + 8)  = *(const u16x8*)(src + 8);
    *(u16x8*)(dst + 16) = *(const u16x8*)(src + 16);
    *(u16x8*)(dst + 24) = *(const u16x8*)(src + 24);
  }
}

// ---------------- flash attention: paired q-tiles (balanced) + reg-prefetch + XCD swizzle ----------------
__global__ __launch_bounds__(256) void attn_kernel(
    const unsigned short* __restrict__ qb, const unsigned short* __restrict__ khat,
    const unsigned short* __restrict__ vt, unsigned short* __restrict__ attnb) {
  __shared__ __align__(16) unsigned short Pbuf[4][2][16 * 72];  // 18432 B
  __shared__ __align__(16) unsigned short Kbuf[64 * 72];        // 9216 B
  __shared__ __align__(16) unsigned short Vbuf[64 * 72];        // 9216 B
  int tid = threadIdx.x, wave = tid >> 6, lane = tid & 63;
  int quad = lane >> 4, col = lane & 15;
  // XCD swizzle: 512 = 8 XCD x 64; 4 bh per XCD -> K/V L2-resident
  int id = blockIdx.y * 16 + blockIdx.x;
  int xcd = id & 7, sidx = id >> 3;
  int bh = xcd * 4 + (sidx >> 4);
  int pi = sidx & 15;
  int b = bh >> 4, h = bh & 15;
  int ta = pi, tb = 31 - pi;    // ta < tb always; every block runs 32 iterations
  int qbA = ta * 64 + wave * 16;
  int qbB = tb * 64 + wave * 16;
  const unsigned short* qrA = qb + ((long)bh * LL + qbA + col) * HDD;
  const unsigned short* qrB = qb + ((long)bh * LL + qbB + col) * HDD;
  bf16x8 aqA0 = *(const bf16x8*)(qrA + quad * 8);
  bf16x8 aqA1 = *(const bf16x8*)(qrA + 32 + quad * 8);
  bf16x8 aqB0 = *(const bf16x8*)(qrB + quad * 8);
  bf16x8 aqB1 = *(const bf16x8*)(qrB + 32 + quad * 8);
  float lA[4] = {0.f, 0.f, 0.f, 0.f}, lB[4] = {0.f, 0.f, 0.f, 0.f};
  f32x4 oA[4] = {}, oB[4] = {};
  unsigned short* PA = Pbuf[wave][0];
  unsigned short* PB = Pbuf[wave][1];
  const unsigned short* kh = khat + (long)bh * LL * HDD;
  const unsigned short* vh = vt + (long)bh * HDD * LL;
  int srow = tid >> 2, sc = (tid & 3) * 8;
  const unsigned short* gK = kh + (long)srow * HDD + sc;
  const unsigned short* gV = vh + (long)srow * LL + sc;
  unsigned short* lK = Kbuf + srow * 72 + sc;
  unsigned short* lV = Vbuf + srow * 72 + sc;
  const float SCL = 0.18033688011112042f;  // log2(e) / 8
  // T14: prefetch tile 0 into regs
  u16x8 rk0 = *(const u16x8*)(gK);
  u16x8 rk1 = *(const u16x8*)(gK + 32);
  u16x8 rv0 = *(const u16x8*)(gV);
  u16x8 rv1 = *(const u16x8*)(gV + 32);
  for (int kt = 0; kt <= tb; kt++) {
    int kbase = kt * 64;
    bool actA = (kt <= ta);
    __syncthreads();
    *(u16x8*)lK        = rk0;
    *(u16x8*)(lK + 32) = rk1;
    *(u16x8*)lV        = rv0;
    *(u16x8*)(lV + 32) = rv1;
    __syncthreads();
    if (kt < tb) {  // issue next-tile loads; latency hides under this tile's compute
      const unsigned short* nK = gK + (long)(kt + 1) * 64 * HDD;
      const unsigned short* nV = gV + (kt + 1) * 64;
      rk0 = *(const u16x8*)(nK);
      rk1 = *(const u16x8*)(nK + 32);
      rv0 = *(const u16x8*)(nV);
      rv1 = *(const u16x8*)(nV + 32);
    }
    f32x4 zA[4], zB[4];
    for (int nt = 0; nt < 4; nt++) {
      const unsigned short* krow = Kbuf + (nt * 16 + col) * 72;
      bf16x8 k0 = *(const bf16x8*)(krow + quad * 8);
      bf16x8 k1 = *(const bf16x8*)(krow + 32 + quad * 8);
      f32x4 z = {};
      z = __builtin_amdgcn_mfma_f32_16x16x32_bf16(aqB0, k0, z, 0, 0, 0);
      z = __builtin_amdgcn_mfma_f32_16x16x32_bf16(aqB1, k1, z, 0, 0, 0);
      zB[nt] = z;
      if (actA) {
        f32x4 y = {};
        y = __builtin_amdgcn_mfma_f32_16x16x32_bf16(aqA0, k0, y, 0, 0, 0);
        y = __builtin_amdgcn_mfma_f32_16x16x32_bf16(aqA1, k1, y, 0, 0, 0);
        zA[nt] = y;
      }
    }
    for (int nt = 0; nt < 4; nt++) {
      int key = kbase + nt * 16 + col;
      for (int r = 0; r < 4; r++) {
        float sc2 = zB[nt][r] * SCL;
        if (kt == tb && key > qbB + quad * 4 + r) sc2 = -1e30f;
        float p = exp2f(sc2);
        lB[r] += p;
        PB[(quad * 4 + r) * 72 + nt * 16 + col] = __builtin_bit_cast(unsigned short, (__bf16)p);
      }
    }
    if (actA) {
      for (int nt = 0; nt < 4; nt++) {
        int key = kbase + nt * 16 + col;
        for (int r = 0; r < 4; r++) {
          float sc2 = zA[nt][r] * SCL;
          if (kt == ta && key > qbA + quad * 4 + r) sc2 = -1e30f;
          float p = exp2f(sc2);
          lA[r] += p;
          PA[(quad * 4 + r) * 72 + nt * 16 + col] = __builtin_bit_cast(unsigned short, (__bf16)p);
        }
      }
    }
    bf16x8 apB0 = *(const bf16x8*)(PB + col * 72 + quad * 8);
    bf16x8 apB1 = *(const bf16x8*)(PB + col * 72 + 32 + quad * 8);
    bf16x8 apA0, apA1;
    if (actA) {
      apA0 = *(const bf16x8*)(PA + col * 72 + quad * 8);
      apA1 = *(const bf16x8*)(PA + col * 72 + 32 + quad * 8);
    }
    for (int nt = 0; nt < 4; nt++) {
      const unsigned short* vrow = Vbuf + (nt * 16 + col) * 72;
      bf16x8 v0 = *(const bf16x8*)(vrow + quad * 8);
      bf16x8 v1 = *(const bf16x8*)(vrow + 32 + quad * 8);
      oB[nt] = __builtin_amdgcn_mfma_f32_16x16x32_bf16(apB0, v0, oB[nt], 0, 0, 0);
      oB[nt] = __builtin_amdgcn_mfma_f32_16x16x32_bf16(apB1, v1, oB[nt], 0, 0, 0);
      if (actA) {
        oA[nt] = __builtin_amdgcn_mfma_f32_16x16x32_bf16(apA0, v0, oA[nt], 0, 0, 0);
        oA[nt] = __builtin_amdgcn_mfma_f32_16x16x32_bf16(apA1, v1, oA[nt], 0, 0, 0);
      }
    }
  }
  float invA[4], invB[4];
  for (int r = 0; r < 4; r++) {
    float t = lA[r];
    t += __shfl_xor(t, 1); t += __shfl_xor(t, 2);
    t += __shfl_xor(t, 4); t += __shfl_xor(t, 8);
    invA[r] = 1.0f / t;
    float u = lB[r];
    u += __shfl_xor(u, 1); u += __shfl_xor(u, 2);
    u += __shfl_xor(u, 4); u += __shfl_xor(u, 8);
    invB[r] = 1.0f / u;
  }
  for (int r = 0; r < 4; r++) {
    int rowA = qbA + quad * 4 + r;
    int rowB = qbB + quad * 4 + r;
    for (int nt = 0; nt < 4; nt++) {
      int hd = nt * 16 + col;
      attnb[((long)b * LL + rowA) * DD + h * HDD + hd] = f2bf(oA[nt][r] * invA[r]);
      attnb[((long)b * LL + rowB) * DD + h * HDD + hd] = f2bf(oB[nt][r] * invB[r]);
    }
  }
}

// ---------------- GEMM2: out = attn * Wo^T (fp32 store) ----------------
__global__ __launch_bounds__(256) void gemm_out(
    const unsigned short* __restrict__ attnb, const unsigned short* __restrict__ wob,
    float* __restrict__ out) {
  __shared__ __align__(16) unsigned short As[128 * 32];
  __shared__ __align__(16) unsigned short Bs[128 * 32];
  int tid = threadIdx.x;
  int wave = tid >> 6, lane = tid & 63;
  int quad = lane >> 4, col = lane & 15;
  int m0 = blockIdx.y * 128;
  int n0 = blockIdx.x * 128;
  f32x4 acc[4][4] = {};
  int row_in = (wave << 4) + (lane >> 2);
  int seg = lane & 3;
  const unsigned short* gA0 = attnb + (long)(m0 + row_in) * DD + seg * 8;
  const unsigned short* gA1 = attnb + (long)(m0 + 64 + row_in) * DD + seg * 8;
  const unsigned short* gB0 = wob + (long)(n0 + row_in) * DD + seg * 8;
  const unsigned short* gB1 = wob + (long)(n0 + 64 + row_in) * DD + seg * 8;
  unsigned short* lA0 = As + wave * 512;
  unsigned short* lA1 = As + 2048 + wave * 512;
  unsigned short* lB0 = Bs + wave * 512;
  unsigned short* lB1 = Bs + 2048 + wave * 512;
  int wm = wave & 1, wn = wave >> 1;
  const unsigned short* pa = As + (wm * 64 + col) * 32 + quad * 8;
  const unsigned short* pb = Bs + (wn * 64 + col) * 32 + quad * 8;
  for (int kk = 0; kk < DD; kk += 32) {
    __syncthreads();
    load_lds16(gA0 + kk, lA0);
    load_lds16(gA1 + kk, lA1);
    load_lds16(gB0 + kk, lB0);
    load_lds16(gB1 + kk, lB1);
    __syncthreads();
    bf16x8 af[4], bfr[4];
    for (int t = 0; t < 4; t++) af[t]  = *(const bf16x8*)(pa + t * 512);
    for (int t = 0; t < 4; t++) bfr[t] = *(const bf16x8*)(pb + t * 512);
    for (int mt = 0; mt < 4; mt++)
      for (int nt = 0; nt < 4; nt++)
        acc[mt][nt] = __builtin_amdgcn_mfma_f32_16x16x32_bf16(af[mt], bfr[nt], acc[mt][nt], 0, 0, 0);
  }
  for (int mt = 0; mt < 4; mt++)
    for (int nt = 0; nt < 4; nt++) {
      int mbase = m0 + wm * 64 + mt * 16 + quad * 4;
      int n = n0 + wn * 64 + nt * 16 + col;
      for (int r = 0; r < 4; r++)
        out[(long)(mbase + r) * DD + n] = acc[mt][nt][r];
    }
}

// ---------------- finalize scalars ----------------
__global__ void finalize(const float* __restrict__ lsum, float* __restrict__ out) {
  if (threadIdx.x == 0) {
    float v = lsum[0] / (float)(BB * HH * LL);
    out[4194304] = v;
    out[4194305] = v;
  }
}

extern "C" void kernel_launch(void* const* d_in, const int* in_sizes, int n_in,
                              void* d_out, int out_size, void* d_ws, size_t ws_size,
                              hipStream_t stream) {
  const float* x  = (const float*)d_in[0];
  const float* wq = (const float*)d_in[1];
  const float* wk = (const float*)d_in[2];
  const float* wv = (const float*)d_in[3];
  const float* wo = (const float*)d_in[4];
  const float* cb = (const float*)d_in[5];
  float* out = (float*)d_out;

  char* ws = (char*)d_ws;
  size_t off = 0;
  auto alloc = [&](size_t bytes) {
    void* p = ws + off;
    off = (off + bytes + 255) & ~(size_t)255;
    return p;
  };
  unsigned short* xb    = (unsigned short*)alloc(4194304 * 2);
  unsigned short* xl    = (unsigned short*)alloc(4194304 * 2);
  unsigned short* wb    = (unsigned short*)alloc(3145728 * 2);
  unsigned short* wkl   = (unsigned short*)alloc(1048576 * 2);
  unsigned short* wob   = (unsigned short*)alloc(1048576 * 2);
  unsigned short* cbb   = (unsigned short*)alloc(524288 * 2);
  unsigned short* cbl   = (unsigned short*)alloc(524288 * 2);
  unsigned short* qb    = (unsigned short*)alloc(4194304 * 2);
  unsigned short* vt    = (unsigned short*)alloc(4194304 * 2);
  unsigned short* khat  = (unsigned short*)alloc(4194304 * 2);
  unsigned short* attnb = (unsigned short*)alloc(4194304 * 2);
  float* c2   = (float*)alloc(8192 * 4);
  float* lsum = (float*)alloc(256);

  cast_all<<<dim3(4096), dim3(256), 0, stream>>>(x, wq, wk, wv, wo, cb, xb, xl, wb, wkl, wob, cbb, cbl, lsum);
  c2_kernel<<<dim3(32), dim3(256), 0, stream>>>(cb, c2);
  gemm_qv<<<dim3(16, 32), dim3(256), 0, stream>>>(xb, wb, qb, vt);
  kvq<<<dim3(16, 32), dim3(256), 0, stream>>>(xb, xl, wb, wkl, cb, c2, cbb, cbl, khat, out + 4194306, lsum);
  attn_kernel<<<dim3(16, 32), dim3(256), 0, stream>>>(qb, khat, vt, attnb);
  gemm_out<<<dim3(8, 32), dim3(256), 0, stream>>>(attnb, wob, out);
  finalize<<<dim3(1), dim3(64), 0, stream>>>(lsum, out);
}

// Round 6
// 290.590 us; speedup vs baseline: 1.1164x; 1.0334x over previous
//
#include <hip/hip_runtime.h>
#include <stdint.h>

#define BB 2
#define HH 16
#define LL 2048
#define DD 1024
#define HDD 64
#define NC 512

typedef __bf16 bf16x8 __attribute__((ext_vector_type(8)));
typedef float f32x4 __attribute__((ext_vector_type(4)));
typedef unsigned short u16x8 __attribute__((ext_vector_type(8)));
typedef unsigned short u16x4 __attribute__((ext_vector_type(4)));

__device__ __forceinline__ unsigned short f2bf(float f) {
  union { float f; unsigned u; } v; v.f = f;
  unsigned u = v.u;
  u += 0x7fffu + ((u >> 16) & 1u);
  return (unsigned short)(u >> 16);
}
__device__ __forceinline__ float bf2f(unsigned short h) {
  union { unsigned u; float f; } v; v.u = ((unsigned)h) << 16;
  return v.f;
}

// async global->LDS, 16B per lane; lds ptr must be wave-uniform base (HW adds lane*16)
__device__ __forceinline__ void load_lds16(const unsigned short* g, unsigned short* l) {
  __builtin_amdgcn_global_load_lds((const __attribute__((address_space(1))) void*)g,
                                   (__attribute__((address_space(3))) void*)l, 16, 0, 0);
}

// ---------------- cast kernel (vectorized: float4 in, u16x4 out) ----------------
__global__ void cast_all(const float* __restrict__ x, const float* __restrict__ wq,
                         const float* __restrict__ wk, const float* __restrict__ wv,
                         const float* __restrict__ wo, const float* __restrict__ cb,
                         unsigned short* __restrict__ xb, unsigned short* __restrict__ xl,
                         unsigned short* __restrict__ wb, unsigned short* __restrict__ wkl,
                         unsigned short* __restrict__ wob, unsigned short* __restrict__ cbb,
                         unsigned short* __restrict__ cbl, float* __restrict__ lsum) {
  long i = (long)blockIdx.x * blockDim.x + threadIdx.x;
  if (i == 0) lsum[0] = 0.f;
  const long NX4 = 1048576, NW4 = 262144, NCB4 = 131072;
  const long TOT4 = NX4 + 4 * NW4 + NCB4;
  for (long q = i; q < TOT4; q += (long)gridDim.x * blockDim.x) {
    if (q < NX4) {
      long t = q * 4;
      float4 v = *(const float4*)(x + t);
      u16x4 hi, lo;
#pragma unroll
      for (int j = 0; j < 4; j++) {
        float f = ((const float*)&v)[j];
        unsigned short h = f2bf(f);
        hi[j] = h; lo[j] = f2bf(f - bf2f(h));
      }
      *(u16x4*)(xb + t) = hi;
      *(u16x4*)(xl + t) = lo;
    } else if (q < NX4 + NW4) {
      long t = (q - NX4) * 4;
      float4 v = *(const float4*)(wq + t);
      u16x4 hi;
#pragma unroll
      for (int j = 0; j < 4; j++) hi[j] = f2bf(((const float*)&v)[j]);
      *(u16x4*)(wb + t) = hi;
    } else if (q < NX4 + 2 * NW4) {
      long t = (q - NX4 - NW4) * 4;
      float4 v = *(const float4*)(wk + t);
      u16x4 hi, lo;
#pragma unroll
      for (int j = 0; j < 4; j++) {
        float f = ((const float*)&v)[j];
        unsigned short h = f2bf(f);
        hi[j] = h; lo[j] = f2bf(f - bf2f(h));
      }
      *(u16x4*)(wb + 1048576 + t) = hi;
      *(u16x4*)(wkl + t) = lo;
    } else if (q < NX4 + 3 * NW4) {
      long t = (q - NX4 - 2 * NW4) * 4;
      float4 v = *(const float4*)(wv + t);
      u16x4 hi;
#pragma unroll
      for (int j = 0; j < 4; j++) hi[j] = f2bf(((const float*)&v)[j]);
      *(u16x4*)(wb + 2097152 + t) = hi;
    } else if (q < NX4 + 4 * NW4) {
      long t = (q - NX4 - 3 * NW4) * 4;
      float4 v = *(const float4*)(wo + t);
      u16x4 hi;
#pragma unroll
      for (int j = 0; j < 4; j++) hi[j] = f2bf(((const float*)&v)[j]);
      *(u16x4*)(wob + t) = hi;
    } else {
      long t = (q - NX4 - 4 * NW4) * 4;
      float4 v = *(const float4*)(cb + t);
      u16x4 hi, lo;
#pragma unroll
      for (int j = 0; j < 4; j++) {
        float f = ((const float*)&v)[j];
        unsigned short h = f2bf(f);
        hi[j] = h; lo[j] = f2bf(f - bf2f(h));
      }
      *(u16x4*)(cbb + t) = hi;
      *(u16x4*)(cbl + t) = lo;
    }
  }
}

// ---------------- codebook norms (fp64 accumulate) ----------------
__global__ void c2_kernel(const float* __restrict__ cb, float* __restrict__ c2) {
  int i = blockIdx.x * blockDim.x + threadIdx.x;
  if (i >= HH * NC) return;
  const float* r = cb + (long)i * HDD;
  double s = 0.0;
  for (int j = 0; j < HDD; j++) s += (double)r[j] * (double)r[j];
  c2[i] = (float)s;
}

// ---------------- GEMM1: Q,V = x * W^T (bf16 MFMA), scatter epilogue ----------------
__global__ __launch_bounds__(256) void gemm_qv(
    const unsigned short* __restrict__ xb, const unsigned short* __restrict__ wb,
    unsigned short* __restrict__ qb, unsigned short* __restrict__ vt) {
  __shared__ __align__(16) unsigned short As[128 * 32];
  __shared__ __align__(16) unsigned short Bs[128 * 32];
  int tid = threadIdx.x;
  int wave = tid >> 6, lane = tid & 63;
  int quad = lane >> 4, col = lane & 15;
  int m0 = blockIdx.y * 128;
  int n0 = blockIdx.x * 128 + (blockIdx.x >= 8 ? 1024 : 0);
  f32x4 acc[4][4] = {};
  int row_in = (wave << 4) + (lane >> 2);
  int seg = lane & 3;
  const unsigned short* gA0 = xb + (long)(m0 + row_in) * DD + seg * 8;
  const unsigned short* gA1 = xb + (long)(m0 + 64 + row_in) * DD + seg * 8;
  const unsigned short* gB0 = wb + (long)(n0 + row_in) * DD + seg * 8;
  const unsigned short* gB1 = wb + (long)(n0 + 64 + row_in) * DD + seg * 8;
  unsigned short* lA0 = As + wave * 512;
  unsigned short* lA1 = As + 2048 + wave * 512;
  unsigned short* lB0 = Bs + wave * 512;
  unsigned short* lB1 = Bs + 2048 + wave * 512;
  int wm = wave & 1, wn = wave >> 1;
  const unsigned short* pa = As + (wm * 64 + col) * 32 + quad * 8;
  const unsigned short* pb = Bs + (wn * 64 + col) * 32 + quad * 8;
  for (int kk = 0; kk < DD; kk += 32) {
    __syncthreads();
    load_lds16(gA0 + kk, lA0);
    load_lds16(gA1 + kk, lA1);
    load_lds16(gB0 + kk, lB0);
    load_lds16(gB1 + kk, lB1);
    __syncthreads();
    bf16x8 af[4], bfr[4];
    for (int t = 0; t < 4; t++) af[t]  = *(const bf16x8*)(pa + t * 512);
    for (int t = 0; t < 4; t++) bfr[t] = *(const bf16x8*)(pb + t * 512);
    for (int mt = 0; mt < 4; mt++)
      for (int nt = 0; nt < 4; nt++)
        acc[mt][nt] = __builtin_amdgcn_mfma_f32_16x16x32_bf16(af[mt], bfr[nt], acc[mt][nt], 0, 0, 0);
  }
  for (int mt = 0; mt < 4; mt++)
    for (int nt = 0; nt < 4; nt++) {
      int mbase = m0 + wm * 64 + mt * 16 + quad * 4;
      int n = n0 + wn * 64 + nt * 16 + col;
      int which = n >> 10, e = n & 1023;
      int h = e >> 6, hd = e & 63;
      for (int r = 0; r < 4; r++) {
        int m = mbase + r;
        int b = m >> 11, l = m & 2047;
        unsigned short val = f2bf(acc[mt][nt][r]);
        long bh = (long)(b * HH + h);
        if (which == 0)      qb[(bh * LL + l) * HDD + hd] = val;
        else                 vt[(bh * HDD + hd) * LL + l] = val;
      }
    }
}

// ---------------- FUSED K-GEMM + VQ (v2: 53248B LDS -> 3 blocks/CU) ----------------
// c2 read direct from global (L2); khat scatter per-wave via shfl (no finalIdx LDS).
__global__ __launch_bounds__(256) void kvq(
    const unsigned short* __restrict__ xb, const unsigned short* __restrict__ xl,
    const unsigned short* __restrict__ wb, const unsigned short* __restrict__ wkl,
    const float* __restrict__ cb, const float* __restrict__ c2,
    const unsigned short* __restrict__ cbb, const unsigned short* __restrict__ cbl,
    unsigned short* __restrict__ khat, float* __restrict__ scodes,
    float* __restrict__ lsum) {
  __shared__ __align__(16) char smem[53248];
  unsigned short* Ah = (unsigned short*)smem;            // 8192 B
  unsigned short* Al = (unsigned short*)(smem + 8192);   // 8192 B
  unsigned short* Bh = (unsigned short*)(smem + 16384);  // 4096 B
  unsigned short* Bl = (unsigned short*)(smem + 20480);  // 4096 B
  float* kfL = (float*)smem;                             // 34816 B = 128*68*4
  unsigned short* CbHb = (unsigned short*)(smem + 34816);// 2 bufs x 4608 B
  unsigned short* CbLb = (unsigned short*)(smem + 44032);// 2 bufs x 4608 B

  int tid = threadIdx.x;
  int wave = tid >> 6, lane = tid & 63;
  int quad = lane >> 4, col = lane & 15;
  // XCD swizzle: group same-m-tile blocks per XCD (x-tile L2 reuse x16)
  int id = blockIdx.y * 16 + blockIdx.x;   // 512 blocks
  int xcd = id & 7, sidx = id >> 3;        // sidx 0..63
  int mt4 = xcd * 4 + (sidx >> 4);         // m-tile 0..31
  int h = sidx & 15;
  int m0 = mt4 * 128;
  int n0 = h * 64;
  int bgl = m0 >> 11;                      // batch
  int l0 = m0 & 2047;
  long bh = (long)(bgl * HH + h);
  const float* c2h = c2 + h * NC;

  // ---------- Phase 1: GEMM ----------
  f32x4 acc[4][2] = {};
  int row_in = (wave << 4) + (lane >> 2);
  int seg = lane & 3;
  const unsigned short* gAh0 = xb + (long)(m0 + row_in) * DD + seg * 8;
  const unsigned short* gAh1 = xb + (long)(m0 + 64 + row_in) * DD + seg * 8;
  const unsigned short* gAl0 = xl + (long)(m0 + row_in) * DD + seg * 8;
  const unsigned short* gAl1 = xl + (long)(m0 + 64 + row_in) * DD + seg * 8;
  const unsigned short* gBh  = wb + (long)(1048576 + (long)(n0 + row_in) * DD) + seg * 8;
  const unsigned short* gBl  = wkl + (long)(n0 + row_in) * DD + seg * 8;
  unsigned short* lAh0 = Ah + wave * 512;
  unsigned short* lAh1 = Ah + 2048 + wave * 512;
  unsigned short* lAl0 = Al + wave * 512;
  unsigned short* lAl1 = Al + 2048 + wave * 512;
  unsigned short* lBh  = Bh + wave * 512;
  unsigned short* lBl  = Bl + wave * 512;
  int wm = wave & 1, wn = wave >> 1;
  const unsigned short* pah = Ah + (wm * 64 + col) * 32 + quad * 8;
  const unsigned short* pal = Al + (wm * 64 + col) * 32 + quad * 8;
  const unsigned short* pbh = Bh + (wn * 32 + col) * 32 + quad * 8;
  const unsigned short* pbl = Bl + (wn * 32 + col) * 32 + quad * 8;
  for (int kk = 0; kk < DD; kk += 32) {
    __syncthreads();
    load_lds16(gAh0 + kk, lAh0);
    load_lds16(gAh1 + kk, lAh1);
    load_lds16(gAl0 + kk, lAl0);
    load_lds16(gAl1 + kk, lAl1);
    load_lds16(gBh + kk, lBh);
    load_lds16(gBl + kk, lBl);
    __syncthreads();
    bf16x8 ah[4], al[4], bhf[2], blf[2];
    for (int t = 0; t < 4; t++) ah[t] = *(const bf16x8*)(pah + t * 512);
    for (int t = 0; t < 4; t++) al[t] = *(const bf16x8*)(pal + t * 512);
    for (int t = 0; t < 2; t++) bhf[t] = *(const bf16x8*)(pbh + t * 512);
    for (int t = 0; t < 2; t++) blf[t] = *(const bf16x8*)(pbl + t * 512);
    for (int mt = 0; mt < 4; mt++)
      for (int nt = 0; nt < 2; nt++) {
        acc[mt][nt] = __builtin_amdgcn_mfma_f32_16x16x32_bf16(ah[mt], bhf[nt], acc[mt][nt], 0, 0, 0);
        acc[mt][nt] = __builtin_amdgcn_mfma_f32_16x16x32_bf16(ah[mt], blf[nt], acc[mt][nt], 0, 0, 0);
        acc[mt][nt] = __builtin_amdgcn_mfma_f32_16x16x32_bf16(al[mt], bhf[nt], acc[mt][nt], 0, 0, 0);
      }
  }
  // ---------- Phase 2: acc -> kfL, stage codebook tile 0 ----------
  __syncthreads();  // all ds_reads of GEMM bufs done before overwrite
  const unsigned short* cbbh = cbb + (long)h * NC * HDD;
  const unsigned short* cblh = cbl + (long)h * NC * HDD;
  int srow = tid >> 3;
  int sseg = (tid & 7) * 8;
  const unsigned short* gH = cbbh + (long)srow * HDD + sseg;
  const unsigned short* gL = cblh + (long)srow * HDD + sseg;
  int ldsOff = srow * 72 + sseg;
  u16x8 ph0 = *(const u16x8*)(gH);
  u16x8 pl0 = *(const u16x8*)(gL);
  for (int mt = 0; mt < 4; mt++)
    for (int nt = 0; nt < 2; nt++) {
      int rbasew = wm * 64 + mt * 16 + quad * 4;
      int hd = wn * 32 + nt * 16 + col;
      for (int r = 0; r < 4; r++)
        kfL[(rbasew + r) * 68 + hd] = acc[mt][nt][r];
    }
  *(u16x8*)(CbHb + ldsOff) = ph0;
  *(u16x8*)(CbLb + ldsOff) = pl0;
  __syncthreads();

  // ---------- Phase 3: VQ rounds ----------
  bf16x8 bfh[2][2], bfl[2][2];
  float k2g[2];
#pragma unroll
  for (int g = 0; g < 2; g++) {
    const float* kp = kfL + (wave * 32 + g * 16 + col) * 68 + quad * 8;
    float4 t0 = *(const float4*)(kp);
    float4 t1 = *(const float4*)(kp + 4);
    float4 t2 = *(const float4*)(kp + 32);
    float4 t3 = *(const float4*)(kp + 36);
    float fv[16];
    fv[0]=t0.x; fv[1]=t0.y; fv[2]=t0.z; fv[3]=t0.w;
    fv[4]=t1.x; fv[5]=t1.y; fv[6]=t1.z; fv[7]=t1.w;
    fv[8]=t2.x; fv[9]=t2.y; fv[10]=t2.z; fv[11]=t2.w;
    fv[12]=t3.x; fv[13]=t3.y; fv[14]=t3.z; fv[15]=t3.w;
    float k2 = 0.f;
#pragma unroll
    for (int j = 0; j < 16; j++) k2 = fmaf(fv[j], fv[j], k2);
    k2 += __shfl_xor(k2, 16);
    k2 += __shfl_xor(k2, 32);
    k2g[g] = k2;
    u16x8 h0, h1, l0u, l1u;
#pragma unroll
    for (int j = 0; j < 8; j++) {
      unsigned short hi = f2bf(fv[j]);
      h0[j] = hi; l0u[j] = f2bf(fv[j] - bf2f(hi));
      unsigned short hi2 = f2bf(fv[8 + j]);
      h1[j] = hi2; l1u[j] = f2bf(fv[8 + j] - bf2f(hi2));
    }
    bfh[g][0] = __builtin_bit_cast(bf16x8, h0);
    bfh[g][1] = __builtin_bit_cast(bf16x8, h1);
    bfl[g][0] = __builtin_bit_cast(bf16x8, l0u);
    bfl[g][1] = __builtin_bit_cast(bf16x8, l1u);
  }
  float b1v[2] = {1e38f, 1e38f}, b2v[2] = {1e38f, 1e38f};
  int b1i[2] = {0x7fffffff, 0x7fffffff}, b2i[2] = {0x7fffffff, 0x7fffffff};
  for (int t = 0; t < 16; t++) {
    int cur = t & 1;
    u16x8 nh, nl;
    if (t < 15) {
      nh = *(const u16x8*)(gH + (t + 1) * 32 * HDD);
      nl = *(const u16x8*)(gL + (t + 1) * 32 * HDD);
    }
    const unsigned short* CbHc = CbHb + cur * 2304;
    const unsigned short* CbLc = CbLb + cur * 2304;
#pragma unroll
    for (int s = 0; s < 2; s++) {
      const unsigned short* rp = CbHc + (s * 16 + col) * 72 + quad * 8;
      const unsigned short* rq = CbLc + (s * 16 + col) * 72 + quad * 8;
      bf16x8 ah0 = *(const bf16x8*)(rp);
      bf16x8 ah1 = *(const bf16x8*)(rp + 32);
      bf16x8 al0 = *(const bf16x8*)(rq);
      bf16x8 al1 = *(const bf16x8*)(rq + 32);
      f32x4 aP0 = {}, aQ0 = {}, aP1 = {}, aQ1 = {};
      aP0 = __builtin_amdgcn_mfma_f32_16x16x32_bf16(ah0, bfh[0][0], aP0, 0, 0, 0);
      aQ0 = __builtin_amdgcn_mfma_f32_16x16x32_bf16(ah1, bfh[0][1], aQ0, 0, 0, 0);
      aP1 = __builtin_amdgcn_mfma_f32_16x16x32_bf16(ah0, bfh[1][0], aP1, 0, 0, 0);
      aQ1 = __builtin_amdgcn_mfma_f32_16x16x32_bf16(ah1, bfh[1][1], aQ1, 0, 0, 0);
      aP0 = __builtin_amdgcn_mfma_f32_16x16x32_bf16(al0, bfh[0][0], aP0, 0, 0, 0);
      aQ0 = __builtin_amdgcn_mfma_f32_16x16x32_bf16(al1, bfh[0][1], aQ0, 0, 0, 0);
      aP1 = __builtin_amdgcn_mfma_f32_16x16x32_bf16(al0, bfh[1][0], aP1, 0, 0, 0);
      aQ1 = __builtin_amdgcn_mfma_f32_16x16x32_bf16(al1, bfh[1][1], aQ1, 0, 0, 0);
      aP0 = __builtin_amdgcn_mfma_f32_16x16x32_bf16(ah0, bfl[0][0], aP0, 0, 0, 0);
      aQ0 = __builtin_amdgcn_mfma_f32_16x16x32_bf16(ah1, bfl[0][1], aQ0, 0, 0, 0);
      aP1 = __builtin_amdgcn_mfma_f32_16x16x32_bf16(ah0, bfl[1][0], aP1, 0, 0, 0);
      aQ1 = __builtin_amdgcn_mfma_f32_16x16x32_bf16(ah1, bfl[1][1], aQ1, 0, 0, 0);
      f32x4 c2v = *(const f32x4*)(c2h + t * 32 + s * 16 + quad * 4);
#pragma unroll
      for (int r = 0; r < 4; r++) {
        int idx = t * 32 + s * 16 + quad * 4 + r;
        float v0 = c2v[r] - 2.0f * (aP0[r] + aQ0[r]);
        if (v0 < b1v[0]) { b2v[0] = b1v[0]; b2i[0] = b1i[0]; b1v[0] = v0; b1i[0] = idx; }
        else if (v0 < b2v[0]) { b2v[0] = v0; b2i[0] = idx; }
        float v1 = c2v[r] - 2.0f * (aP1[r] + aQ1[r]);
        if (v1 < b1v[1]) { b2v[1] = b1v[1]; b2i[1] = b1i[1]; b1v[1] = v1; b1i[1] = idx; }
        else if (v1 < b2v[1]) { b2v[1] = v1; b2i[1] = idx; }
      }
    }
    if (t < 15) {
      *(u16x8*)(CbHb + (cur ^ 1) * 2304 + ldsOff) = nh;
      *(u16x8*)(CbLb + (cur ^ 1) * 2304 + ldsOff) = nl;
    }
    __syncthreads();
  }
  const float DMARG = 0.015625f;
  float partT = 0.f;
  int w0 = 0, w1 = 0;
#pragma unroll
  for (int g = 0; g < 2; g++) {
    float v1 = b1v[g], v2 = b2v[g];
    int i1 = b1i[g], i2 = b2i[g];
#pragma unroll
    for (int d = 16; d <= 32; d <<= 1) {
      float o1v = __shfl_xor(v1, d); int o1i = __shfl_xor(i1, d);
      float o2v = __shfl_xor(v2, d); int o2i = __shfl_xor(i2, d);
      if (o1v < v1 || (o1v == v1 && o1i < i1)) {
        float nv; int ni;
        if (v1 < o2v || (v1 == o2v && i1 < o2i)) { nv = v1; ni = i1; }
        else { nv = o2v; ni = o2i; }
        v1 = o1v; i1 = o1i; v2 = nv; i2 = ni;
      } else {
        if (o1v < v2 || (o1v == v2 && o1i < i2)) { v2 = o1v; i2 = o1i; }
      }
    }
    bool trig = (v2 - v1 <= DMARG);
    float part;
    int widx = i1;
    if (__any(trig)) {
      const float* kpr = kfL + (wave * 32 + g * 16 + col) * 68 + quad * 8;
      float4 f0 = *(const float4*)(kpr);
      float4 f1 = *(const float4*)(kpr + 4);
      float4 f2 = *(const float4*)(kpr + 32);
      float4 f3 = *(const float4*)(kpr + 36);
      const float* c1p = cb + ((long)h * NC + i1) * HDD + quad * 8;
      const float* c2p = cb + ((long)h * NC + i2) * HDD + quad * 8;
      float4 a0 = *(const float4*)(c1p);
      float4 a1 = *(const float4*)(c1p + 4);
      float4 a2 = *(const float4*)(c1p + 32);
      float4 a3 = *(const float4*)(c1p + 36);
      float4 e0 = *(const float4*)(c2p);
      float4 e1 = *(const float4*)(c2p + 4);
      float4 e2 = *(const float4*)(c2p + 32);
      float4 e3 = *(const float4*)(c2p + 36);
      float s1 = 0.f, s2 = 0.f;
#pragma unroll
      for (int j = 0; j < 4; j++) {
        float d;
        d = ((const float*)&f0)[j] - ((const float*)&a0)[j]; s1 = fmaf(d, d, s1);
        d = ((const float*)&f1)[j] - ((const float*)&a1)[j]; s1 = fmaf(d, d, s1);
        d = ((const float*)&f2)[j] - ((const float*)&a2)[j]; s1 = fmaf(d, d, s1);
        d = ((const float*)&f3)[j] - ((const float*)&a3)[j]; s1 = fmaf(d, d, s1);
        d = ((const float*)&f0)[j] - ((const float*)&e0)[j]; s2 = fmaf(d, d, s2);
        d = ((const float*)&f1)[j] - ((const float*)&e1)[j]; s2 = fmaf(d, d, s2);
        d = ((const float*)&f2)[j] - ((const float*)&e2)[j]; s2 = fmaf(d, d, s2);
        d = ((const float*)&f3)[j] - ((const float*)&e3)[j]; s2 = fmaf(d, d, s2);
      }
      s1 += __shfl_xor(s1, 16); s1 += __shfl_xor(s1, 32);
      s2 += __shfl_xor(s2, 16); s2 += __shfl_xor(s2, 32);
      if (trig) {
        if (s2 < s1 || (s2 == s1 && i2 < i1)) { widx = i2; part = s2; }
        else { widx = i1; part = s1; }
      } else {
        part = k2g[g] + v1;
      }
    } else {
      part = k2g[g] + v1;
    }
    if (g == 0) w0 = widx; else w1 = widx;
    if (quad == 0) partT += part;
    if (lane < 16)
      scodes[bh * LL + l0 + wave * 32 + g * 16 + lane] = (float)widx;
  }
  partT += __shfl_xor(partT, 1);  partT += __shfl_xor(partT, 2);
  partT += __shfl_xor(partT, 4);  partT += __shfl_xor(partT, 8);
  partT += __shfl_xor(partT, 16); partT += __shfl_xor(partT, 32);
  if (lane == 0) atomicAdd(lsum, partT);
  // per-wave khat scatter via shfl (no LDS, no barrier)
  {
    int rL = lane >> 1;                 // 0..31: row within wave's 32 rows
    int srcl = rL & 15;
    int c0 = __shfl(w0, srcl);
    int c1 = __shfl(w1, srcl);
    int code = (rL >> 4) ? c1 : c0;
    int p = (lane & 1) * 32;
    const unsigned short* src = cbbh + (long)code * HDD + p;
    unsigned short* dst = khat + (bh * LL + l0 + wave * 32 + rL) * HDD + p;
    *(u16x8*)(dst)      = *(const u16x8*)(src);
    *(u16x8*)(dst + 8)  = *(const u16x8*)(src + 8);
    *(u16x8*)(dst + 16) = *(const u16x8*)(src + 16);
    *(u16x8*)(dst + 24) = *(const u16x8*)(src + 24);
  }
}

// ---------------- flash attention: paired q-tiles + swapped QK^T (key-major softmax) ----------------
// mfma(K,Q): C rows = keys, cols = q-rows -> per-lane 4 consecutive keys; P store is one
// ds_write_b64 per nt; denominator is a per-lane scalar. P layout [q-row][key] unchanged,
// so the PV side is identical. Same exp2 values; only fp32-sum reordering.
__global__ __launch_bounds__(256) void attn_kernel(
    const unsigned short* __restrict__ qb, const unsigned short* __restrict__ khat,
    const unsigned short* __restrict__ vt, unsigned short* __restrict__ attnb) {
  __shared__ __align__(16) unsigned short Pbuf[4][2][16 * 72];  // 18432 B
  __shared__ __align__(16) unsigned short Kbuf[64 * 72];        // 9216 B
  __shared__ __align__(16) unsigned short Vbuf[64 * 72];        // 9216 B
  int tid = threadIdx.x, wave = tid >> 6, lane = tid & 63;
  int quad = lane >> 4, col = lane & 15;
  // XCD swizzle: 512 = 8 XCD x 64; 4 bh per XCD -> K/V L2-resident
  int id = blockIdx.y * 16 + blockIdx.x;
  int xcd = id & 7, sidx = id >> 3;
  int bh = xcd * 4 + (sidx >> 4);
  int pi = sidx & 15;
  int b = bh >> 4, h = bh & 15;
  int ta = pi, tb = 31 - pi;    // ta < tb; every block does 33 tile-units of work
  int qbA = ta * 64 + wave * 16;
  int qbB = tb * 64 + wave * 16;
  const unsigned short* qrA = qb + ((long)bh * LL + qbA + col) * HDD;
  const unsigned short* qrB = qb + ((long)bh * LL + qbB + col) * HDD;
  bf16x8 aqA0 = *(const bf16x8*)(qrA + quad * 8);
  bf16x8 aqA1 = *(const bf16x8*)(qrA + 32 + quad * 8);
  bf16x8 aqB0 = *(const bf16x8*)(qrB + quad * 8);
  bf16x8 aqB1 = *(const bf16x8*)(qrB + 32 + quad * 8);
  float lA = 0.f, lB = 0.f;     // per-lane scalar denom (q-row = col)
  f32x4 oA[4] = {}, oB[4] = {};
  unsigned short* PA = Pbuf[wave][0];
  unsigned short* PB = Pbuf[wave][1];
  const unsigned short* kh = khat + (long)bh * LL * HDD;
  const unsigned short* vh = vt + (long)bh * HDD * LL;
  int srow = tid >> 2, sc = (tid & 3) * 8;
  const unsigned short* gK = kh + (long)srow * HDD + sc;
  const unsigned short* gV = vh + (long)srow * LL + sc;
  unsigned short* lK = Kbuf + srow * 72 + sc;
  unsigned short* lV = Vbuf + srow * 72 + sc;
  const float SCL = 0.18033688011112042f;  // log2(e) / 8
  // T14: prefetch tile 0 into regs
  u16x8 rk0 = *(const u16x8*)(gK);
  u16x8 rk1 = *(const u16x8*)(gK + 32);
  u16x8 rv0 = *(const u16x8*)(gV);
  u16x8 rv1 = *(const u16x8*)(gV + 32);
  for (int kt = 0; kt <= tb; kt++) {
    int kbase = kt * 64;
    bool actA = (kt <= ta);
    __syncthreads();
    *(u16x8*)lK        = rk0;
    *(u16x8*)(lK + 32) = rk1;
    *(u16x8*)lV        = rv0;
    *(u16x8*)(lV + 32) = rv1;
    __syncthreads();
    if (kt < tb) {  // issue next-tile loads; latency hides under this tile's compute
      const unsigned short* nK = gK + (long)(kt + 1) * 64 * HDD;
      const unsigned short* nV = gV + (kt + 1) * 64;
      rk0 = *(const u16x8*)(nK);
      rk1 = *(const u16x8*)(nK + 32);
      rv0 = *(const u16x8*)(nV);
      rv1 = *(const u16x8*)(nV + 32);
    }
    f32x4 zA[4], zB[4];
    for (int nt = 0; nt < 4; nt++) {
      const unsigned short* krow = Kbuf + (nt * 16 + col) * 72;
      bf16x8 k0 = *(const bf16x8*)(krow + quad * 8);
      bf16x8 k1 = *(const bf16x8*)(krow + 32 + quad * 8);
      f32x4 z = {};
      z = __builtin_amdgcn_mfma_f32_16x16x32_bf16(k0, aqB0, z, 0, 0, 0);
      z = __builtin_amdgcn_mfma_f32_16x16x32_bf16(k1, aqB1, z, 0, 0, 0);
      zB[nt] = z;
      if (actA) {
        f32x4 y = {};
        y = __builtin_amdgcn_mfma_f32_16x16x32_bf16(k0, aqA0, y, 0, 0, 0);
        y = __builtin_amdgcn_mfma_f32_16x16x32_bf16(k1, aqA1, y, 0, 0, 0);
        zA[nt] = y;
      }
    }
    // key-major softmax: lane holds keys {kbase+nt*16+quad*4+r} for q-row col
    for (int nt = 0; nt < 4; nt++) {
      u16x4 pk;
      for (int r = 0; r < 4; r++) {
        float sc2 = zB[nt][r] * SCL;
        int key = kbase + nt * 16 + quad * 4 + r;
        if (kt == tb && key > qbB + col) sc2 = -1e30f;
        float p = exp2f(sc2);
        lB += p;
        pk[r] = __builtin_bit_cast(unsigned short, (__bf16)p);
      }
      *(u16x4*)(PB + col * 72 + nt * 16 + quad * 4) = pk;
    }
    if (actA) {
      for (int nt = 0; nt < 4; nt++) {
        u16x4 pk;
        for (int r = 0; r < 4; r++) {
          float sc2 = zA[nt][r] * SCL;
          int key = kbase + nt * 16 + quad * 4 + r;
          if (kt == ta && key > qbA + col) sc2 = -1e30f;
          float p = exp2f(sc2);
          lA += p;
          pk[r] = __builtin_bit_cast(unsigned short, (__bf16)p);
        }
        *(u16x4*)(PA + col * 72 + nt * 16 + quad * 4) = pk;
      }
    }
    bf16x8 apB0 = *(const bf16x8*)(PB + col * 72 + quad * 8);
    bf16x8 apB1 = *(const bf16x8*)(PB + col * 72 + 32 + quad * 8);
    bf16x8 apA0, apA1;
    if (actA) {
      apA0 = *(const bf16x8*)(PA + col * 72 + quad * 8);
      apA1 = *(const bf16x8*)(PA + col * 72 + 32 + quad * 8);
    }
    for (int nt = 0; nt < 4; nt++) {
      const unsigned short* vrow = Vbuf + (nt * 16 + col) * 72;
      bf16x8 v0 = *(const bf16x8*)(vrow + quad * 8);
      bf16x8 v1 = *(const bf16x8*)(vrow + 32 + quad * 8);
      oB[nt] = __builtin_amdgcn_mfma_f32_16x16x32_bf16(apB0, v0, oB[nt], 0, 0, 0);
      oB[nt] = __builtin_amdgcn_mfma_f32_16x16x32_bf16(apB1, v1, oB[nt], 0, 0, 0);
      if (actA) {
        oA[nt] = __builtin_amdgcn_mfma_f32_16x16x32_bf16(apA0, v0, oA[nt], 0, 0, 0);
        oA[nt] = __builtin_amdgcn_mfma_f32_16x16x32_bf16(apA1, v1, oA[nt], 0, 0, 0);
      }
    }
  }
  // reduce per-lane denoms (sum over the 4 quad-copies of each q-row)
  lA += __shfl_xor(lA, 16); lA += __shfl_xor(lA, 32);
  lB += __shfl_xor(lB, 16); lB += __shfl_xor(lB, 32);
  float invAc = 1.0f / lA;
  float invBc = 1.0f / lB;
  for (int r = 0; r < 4; r++) {
    float invA = __shfl(invAc, quad * 4 + r);   // inv for q-row quad*4+r
    float invB = __shfl(invBc, quad * 4 + r);
    int rowA = qbA + quad * 4 + r;
    int rowB = qbB + quad * 4 + r;
    for (int nt = 0; nt < 4; nt++) {
      int hd = nt * 16 + col;
      attnb[((long)b * LL + rowA) * DD + h * HDD + hd] = f2bf(oA[nt][r] * invA);
      attnb[((long)b * LL + rowB) * DD + h * HDD + hd] = f2bf(oB[nt][r] * invB);
    }
  }
}

// ---------------- GEMM2: out = attn * Wo^T (fp32 store) ----------------
__global__ __launch_bounds__(256) void gemm_out(
    const unsigned short* __restrict__ attnb, const unsigned short* __restrict__ wob,
    float* __restrict__ out) {
  __shared__ __align__(16) unsigned short As[128 * 32];
  __shared__ __align__(16) unsigned short Bs[128 * 32];
  int tid = threadIdx.x;
  int wave = tid >> 6, lane = tid & 63;
  int quad = lane >> 4, col = lane & 15;
  int m0 = blockIdx.y * 128;
  int n0 = blockIdx.x * 128;
  f32x4 acc[4][4] = {};
  int row_in = (wave << 4) + (lane >> 2);
  int seg = lane & 3;
  const unsigned short* gA0 = attnb + (long)(m0 + row_in) * DD + seg * 8;
  const unsigned short* gA1 = attnb + (long)(m0 + 64 + row_in) * DD + seg * 8;
  const unsigned short* gB0 = wob + (long)(n0 + row_in) * DD + seg * 8;
  const unsigned short* gB1 = wob + (long)(n0 + 64 + row_in) * DD + seg * 8;
  unsigned short* lA0 = As + wave * 512;
  unsigned short* lA1 = As + 2048 + wave * 512;
  unsigned short* lB0 = Bs + wave * 512;
  unsigned short* lB1 = Bs + 2048 + wave * 512;
  int wm = wave & 1, wn = wave >> 1;
  const unsigned short* pa = As + (wm * 64 + col) * 32 + quad * 8;
  const unsigned short* pb = Bs + (wn * 64 + col) * 32 + quad * 8;
  for (int kk = 0; kk < DD; kk += 32) {
    __syncthreads();
    load_lds16(gA0 + kk, lA0);
    load_lds16(gA1 + kk, lA1);
    load_lds16(gB0 + kk, lB0);
    load_lds16(gB1 + kk, lB1);
    __syncthreads();
    bf16x8 af[4], bfr[4];
    for (int t = 0; t < 4; t++) af[t]  = *(const bf16x8*)(pa + t * 512);
    for (int t = 0; t < 4; t++) bfr[t] = *(const bf16x8*)(pb + t * 512);
    for (int mt = 0; mt < 4; mt++)
      for (int nt = 0; nt < 4; nt++)
        acc[mt][nt] = __builtin_amdgcn_mfma_f32_16x16x32_bf16(af[mt], bfr[nt], acc[mt][nt], 0, 0, 0);
  }
  for (int mt = 0; mt < 4; mt++)
    for (int nt = 0; nt < 4; nt++) {
      int mbase = m0 + wm * 64 + mt * 16 + quad * 4;
      int n = n0 + wn * 64 + nt * 16 + col;
      for (int r = 0; r < 4; r++)
        out[(long)(mbase + r) * DD + n] = acc[mt][nt][r];
    }
}

// ---------------- finalize scalars ----------------
__global__ void finalize(const float* __restrict__ lsum, float* __restrict__ out) {
  if (threadIdx.x == 0) {
    float v = lsum[0] / (float)(BB * HH * LL);
    out[4194304] = v;
    out[4194305] = v;
  }
}

extern "C" void kernel_launch(void* const* d_in, const int* in_sizes, int n_in,
                              void* d_out, int out_size, void* d_ws, size_t ws_size,
                              hipStream_t stream) {
  const float* x  = (const float*)d_in[0];
  const float* wq = (const float*)d_in[1];
  const float* wk = (const float*)d_in[2];
  const float* wv = (const float*)d_in[3];
  const float* wo = (const float*)d_in[4];
  const float* cb = (const float*)d_in[5];
  float* out = (float*)d_out;

  char* ws = (char*)d_ws;
  size_t off = 0;
  auto alloc = [&](size_t bytes) {
    void* p = ws + off;
    off = (off + bytes + 255) & ~(size_t)255;
    return p;
  };
  unsigned short* xb    = (unsigned short*)alloc(4194304 * 2);
  unsigned short* xl    = (unsigned short*)alloc(4194304 * 2);
  unsigned short* wb    = (unsigned short*)alloc(3145728 * 2);
  unsigned short* wkl   = (unsigned short*)alloc(1048576 * 2);
  unsigned short* wob   = (unsigned short*)alloc(1048576 * 2);
  unsigned short* cbb   = (unsigned short*)alloc(524288 * 2);
  unsigned short* cbl   = (unsigned short*)alloc(524288 * 2);
  unsigned short* qb    = (unsigned short*)alloc(4194304 * 2);
  unsigned short* vt    = (unsigned short*)alloc(4194304 * 2);
  unsigned short* khat  = (unsigned short*)alloc(4194304 * 2);
  unsigned short* attnb = (unsigned short*)alloc(4194304 * 2);
  float* c2   = (float*)alloc(8192 * 4);
  float* lsum = (float*)alloc(256);

  cast_all<<<dim3(4096), dim3(256), 0, stream>>>(x, wq, wk, wv, wo, cb, xb, xl, wb, wkl, wob, cbb, cbl, lsum);
  c2_kernel<<<dim3(32), dim3(256), 0, stream>>>(cb, c2);
  gemm_qv<<<dim3(16, 32), dim3(256), 0, stream>>>(xb, wb, qb, vt);
  kvq<<<dim3(16, 32), dim3(256), 0, stream>>>(xb, xl, wb, wkl, cb, c2, cbb, cbl, khat, out + 4194306, lsum);
  attn_kernel<<<dim3(16, 32), dim3(256), 0, stream>>>(qb, khat, vt, attnb);
  gemm_out<<<dim3(8, 32), dim3(256), 0, stream>>>(attnb, wob, out);
  finalize<<<dim3(1), dim3(64), 0, stream>>>(lsum, out);
}

// Round 7
// 275.570 us; speedup vs baseline: 1.1773x; 1.0545x over previous
//
#include <hip/hip_runtime.h>
#include <stdint.h>

#define BB 2
#define HH 16
#define LL 2048
#define DD 1024
#define HDD 64
#define NC 512

typedef __bf16 bf16x8 __attribute__((ext_vector_type(8)));
typedef float f32x4 __attribute__((ext_vector_type(4)));
typedef unsigned short u16x8 __attribute__((ext_vector_type(8)));
typedef unsigned short u16x4 __attribute__((ext_vector_type(4)));

__device__ __forceinline__ unsigned short f2bf(float f) {
  union { float f; unsigned u; } v; v.f = f;
  unsigned u = v.u;
  u += 0x7fffu + ((u >> 16) & 1u);
  return (unsigned short)(u >> 16);
}
__device__ __forceinline__ float bf2f(unsigned short h) {
  union { unsigned u; float f; } v; v.u = ((unsigned)h) << 16;
  return v.f;
}

// async global->LDS, 16B per lane; lds ptr must be wave-uniform base (HW adds lane*16)
__device__ __forceinline__ void load_lds16(const unsigned short* g, unsigned short* l) {
  __builtin_amdgcn_global_load_lds((const __attribute__((address_space(1))) void*)g,
                                   (__attribute__((address_space(3))) void*)l, 16, 0, 0);
}

// ---------------- cast kernel (vectorized) + fused c2 norms ----------------
__global__ void cast_all(const float* __restrict__ x, const float* __restrict__ wq,
                         const float* __restrict__ wk, const float* __restrict__ wv,
                         const float* __restrict__ wo, const float* __restrict__ cb,
                         unsigned short* __restrict__ xb, unsigned short* __restrict__ xl,
                         unsigned short* __restrict__ wb, unsigned short* __restrict__ wkl,
                         unsigned short* __restrict__ wob, unsigned short* __restrict__ cbb,
                         unsigned short* __restrict__ cbl, float* __restrict__ c2,
                         float* __restrict__ lsum) {
  if (blockIdx.x >= 4096) {  // c2 blocks (32 x 256 threads)
    int i = (blockIdx.x - 4096) * 256 + threadIdx.x;
    if (i < HH * NC) {
      const float* r = cb + (long)i * HDD;
      double s = 0.0;
      for (int j = 0; j < HDD; j++) s += (double)r[j] * (double)r[j];
      c2[i] = (float)s;
    }
    return;
  }
  long i = (long)blockIdx.x * blockDim.x + threadIdx.x;
  if (i == 0) lsum[0] = 0.f;
  const long NX4 = 1048576, NW4 = 262144, NCB4 = 131072;
  const long TOT4 = NX4 + 4 * NW4 + NCB4;
  for (long q = i; q < TOT4; q += (long)4096 * blockDim.x) {
    if (q < NX4) {
      long t = q * 4;
      float4 v = *(const float4*)(x + t);
      u16x4 hi, lo;
#pragma unroll
      for (int j = 0; j < 4; j++) {
        float f = ((const float*)&v)[j];
        unsigned short h = f2bf(f);
        hi[j] = h; lo[j] = f2bf(f - bf2f(h));
      }
      *(u16x4*)(xb + t) = hi;
      *(u16x4*)(xl + t) = lo;
    } else if (q < NX4 + NW4) {
      long t = (q - NX4) * 4;
      float4 v = *(const float4*)(wq + t);
      u16x4 hi;
#pragma unroll
      for (int j = 0; j < 4; j++) hi[j] = f2bf(((const float*)&v)[j]);
      *(u16x4*)(wb + t) = hi;
    } else if (q < NX4 + 2 * NW4) {
      long t = (q - NX4 - NW4) * 4;
      float4 v = *(const float4*)(wk + t);
      u16x4 hi, lo;
#pragma unroll
      for (int j = 0; j < 4; j++) {
        float f = ((const float*)&v)[j];
        unsigned short h = f2bf(f);
        hi[j] = h; lo[j] = f2bf(f - bf2f(h));
      }
      *(u16x4*)(wb + 1048576 + t) = hi;
      *(u16x4*)(wkl + t) = lo;
    } else if (q < NX4 + 3 * NW4) {
      long t = (q - NX4 - 2 * NW4) * 4;
      float4 v = *(const float4*)(wv + t);
      u16x4 hi;
#pragma unroll
      for (int j = 0; j < 4; j++) hi[j] = f2bf(((const float*)&v)[j]);
      *(u16x4*)(wb + 2097152 + t) = hi;
    } else if (q < NX4 + 4 * NW4) {
      long t = (q - NX4 - 3 * NW4) * 4;
      float4 v = *(const float4*)(wo + t);
      u16x4 hi;
#pragma unroll
      for (int j = 0; j < 4; j++) hi[j] = f2bf(((const float*)&v)[j]);
      *(u16x4*)(wob + t) = hi;
    } else {
      long t = (q - NX4 - 4 * NW4) * 4;
      float4 v = *(const float4*)(cb + t);
      u16x4 hi, lo;
#pragma unroll
      for (int j = 0; j < 4; j++) {
        float f = ((const float*)&v)[j];
        unsigned short h = f2bf(f);
        hi[j] = h; lo[j] = f2bf(f - bf2f(h));
      }
      *(u16x4*)(cbb + t) = hi;
      *(u16x4*)(cbl + t) = lo;
    }
  }
}

// ---------------- HORIZONTAL FUSION: gemm_qv (512 blocks) + kvq-64row (1024 blocks) ----------------
// gid%3==2 -> qv block; else kvq block. 37888B LDS union -> 4 blocks/CU; mixed
// residency lets QV's barrier stalls overlap KVQ's and vice versa.
__global__ __launch_bounds__(256) void qv_kvq(
    const unsigned short* __restrict__ xb, const unsigned short* __restrict__ xl,
    const unsigned short* __restrict__ wb, const unsigned short* __restrict__ wkl,
    const float* __restrict__ cb, const float* __restrict__ c2,
    const unsigned short* __restrict__ cbb, const unsigned short* __restrict__ cbl,
    unsigned short* __restrict__ qb, unsigned short* __restrict__ vt,
    unsigned short* __restrict__ khat, float* __restrict__ scodes,
    float* __restrict__ lsum) {
  __shared__ __align__(16) char smem[37888];
  int tid = threadIdx.x;
  int wave = tid >> 6, lane = tid & 63;
  int quad = lane >> 4, col = lane & 15;
  int gid = blockIdx.x;
  int cls = gid % 3;

  if (cls == 2) {
    // ================= QV path (identical math to gemm_qv) =================
    unsigned short* As = (unsigned short*)smem;           // 8192 B
    unsigned short* Bs = (unsigned short*)(smem + 8192);  // 8192 B
    int qid = gid / 3;                 // 0..511
    int bx = qid & 15, by = qid >> 4;
    int m0 = by * 128;
    int n0 = bx * 128 + (bx >= 8 ? 1024 : 0);
    f32x4 acc[4][4] = {};
    int row_in = (wave << 4) + (lane >> 2);
    int seg = lane & 3;
    const unsigned short* gA0 = xb + (long)(m0 + row_in) * DD + seg * 8;
    const unsigned short* gA1 = xb + (long)(m0 + 64 + row_in) * DD + seg * 8;
    const unsigned short* gB0 = wb + (long)(n0 + row_in) * DD + seg * 8;
    const unsigned short* gB1 = wb + (long)(n0 + 64 + row_in) * DD + seg * 8;
    unsigned short* lA0 = As + wave * 512;
    unsigned short* lA1 = As + 2048 + wave * 512;
    unsigned short* lB0 = Bs + wave * 512;
    unsigned short* lB1 = Bs + 2048 + wave * 512;
    int wm = wave & 1, wn = wave >> 1;
    const unsigned short* pa = As + (wm * 64 + col) * 32 + quad * 8;
    const unsigned short* pb = Bs + (wn * 64 + col) * 32 + quad * 8;
    for (int kk = 0; kk < DD; kk += 32) {
      __syncthreads();
      load_lds16(gA0 + kk, lA0);
      load_lds16(gA1 + kk, lA1);
      load_lds16(gB0 + kk, lB0);
      load_lds16(gB1 + kk, lB1);
      __syncthreads();
      bf16x8 af[4], bfr[4];
      for (int t = 0; t < 4; t++) af[t]  = *(const bf16x8*)(pa + t * 512);
      for (int t = 0; t < 4; t++) bfr[t] = *(const bf16x8*)(pb + t * 512);
      for (int mt = 0; mt < 4; mt++)
        for (int nt = 0; nt < 4; nt++)
          acc[mt][nt] = __builtin_amdgcn_mfma_f32_16x16x32_bf16(af[mt], bfr[nt], acc[mt][nt], 0, 0, 0);
    }
    for (int mt = 0; mt < 4; mt++)
      for (int nt = 0; nt < 4; nt++) {
        int mbase = m0 + wm * 64 + mt * 16 + quad * 4;
        int n = n0 + wn * 64 + nt * 16 + col;
        int which = n >> 10, e = n & 1023;
        int h = e >> 6, hd = e & 63;
        for (int r = 0; r < 4; r++) {
          int m = mbase + r;
          int b = m >> 11, l = m & 2047;
          unsigned short val = f2bf(acc[mt][nt][r]);
          long bh = (long)(b * HH + h);
          if (which == 0)      qb[(bh * LL + l) * HDD + hd] = val;
          else                 vt[(bh * HDD + hd) * LL + l] = val;
        }
      }
    return;
  }

  // ================= KVQ path: 64-row m-tile, fused GEMM+VQ =================
  unsigned short* Ah = (unsigned short*)smem;            // 4096 B
  unsigned short* Al = (unsigned short*)(smem + 4096);   // 4096 B
  unsigned short* Bh = (unsigned short*)(smem + 8192);   // 4096 B
  unsigned short* Bl = (unsigned short*)(smem + 12288);  // 4096 B
  float* kfL = (float*)smem;                             // 17408 B = 64*68*4 (overlays staging)
  unsigned short* CbHb = (unsigned short*)(smem + 17408);// 2 bufs x 4608 B
  unsigned short* CbLb = (unsigned short*)(smem + 26624);// 2 bufs x 4608 B
  float* Cs = (float*)(smem + 35840);                    // 2048 B

  int kid = (gid / 3) * 2 + cls;       // 0..1023
  int mtile = kid & 63;                // 0..63
  int h = kid >> 6;                    // 0..15
  int m0 = mtile * 64;
  int n0 = h * 64;
  int bgl = m0 >> 11;
  int l0 = m0 & 2047;
  long bh = (long)(bgl * HH + h);
  const float* c2h = c2 + h * NC;
  Cs[tid] = c2h[tid];
  Cs[tid + 256] = c2h[tid + 256];

  // ---------- Phase 1: GEMM 64x64 (split-bf16 3-pass) ----------
  f32x4 acc[2][2] = {};
  int row_in = (wave << 4) + (lane >> 2);   // 0..63
  int seg = lane & 3;
  const unsigned short* gAh = xb + (long)(m0 + row_in) * DD + seg * 8;
  const unsigned short* gAl = xl + (long)(m0 + row_in) * DD + seg * 8;
  const unsigned short* gBh = wb + (long)(1048576 + (long)(n0 + row_in) * DD) + seg * 8;
  const unsigned short* gBl = wkl + (long)(n0 + row_in) * DD + seg * 8;
  unsigned short* lAh = Ah + wave * 512;
  unsigned short* lAl = Al + wave * 512;
  unsigned short* lBh = Bh + wave * 512;
  unsigned short* lBl = Bl + wave * 512;
  int wm = wave & 1, wn = wave >> 1;
  const unsigned short* pah = Ah + (wm * 32 + col) * 32 + quad * 8;
  const unsigned short* pal = Al + (wm * 32 + col) * 32 + quad * 8;
  const unsigned short* pbh = Bh + (wn * 32 + col) * 32 + quad * 8;
  const unsigned short* pbl = Bl + (wn * 32 + col) * 32 + quad * 8;
  for (int kk = 0; kk < DD; kk += 32) {
    __syncthreads();
    load_lds16(gAh + kk, lAh);
    load_lds16(gAl + kk, lAl);
    load_lds16(gBh + kk, lBh);
    load_lds16(gBl + kk, lBl);
    __syncthreads();
    bf16x8 ah[2], al[2], bhf[2], blf[2];
    for (int t = 0; t < 2; t++) ah[t] = *(const bf16x8*)(pah + t * 512);
    for (int t = 0; t < 2; t++) al[t] = *(const bf16x8*)(pal + t * 512);
    for (int t = 0; t < 2; t++) bhf[t] = *(const bf16x8*)(pbh + t * 512);
    for (int t = 0; t < 2; t++) blf[t] = *(const bf16x8*)(pbl + t * 512);
    for (int mt = 0; mt < 2; mt++)
      for (int nt = 0; nt < 2; nt++) {
        acc[mt][nt] = __builtin_amdgcn_mfma_f32_16x16x32_bf16(ah[mt], bhf[nt], acc[mt][nt], 0, 0, 0);
        acc[mt][nt] = __builtin_amdgcn_mfma_f32_16x16x32_bf16(ah[mt], blf[nt], acc[mt][nt], 0, 0, 0);
        acc[mt][nt] = __builtin_amdgcn_mfma_f32_16x16x32_bf16(al[mt], bhf[nt], acc[mt][nt], 0, 0, 0);
      }
  }
  // ---------- Phase 2: acc -> kfL[64][68]; stage codebook tile 0 ----------
  __syncthreads();
  const unsigned short* cbbh = cbb + (long)h * NC * HDD;
  const unsigned short* cblh = cbl + (long)h * NC * HDD;
  int srow = tid >> 3;
  int sseg = (tid & 7) * 8;
  const unsigned short* gH = cbbh + (long)srow * HDD + sseg;
  const unsigned short* gL = cblh + (long)srow * HDD + sseg;
  int ldsOff = srow * 72 + sseg;
  u16x8 ph0 = *(const u16x8*)(gH);
  u16x8 pl0 = *(const u16x8*)(gL);
  for (int mt = 0; mt < 2; mt++)
    for (int nt = 0; nt < 2; nt++) {
      int rw = wm * 32 + mt * 16 + quad * 4;
      int hd = wn * 32 + nt * 16 + col;
      for (int r = 0; r < 4; r++)
        kfL[(rw + r) * 68 + hd] = acc[mt][nt][r];
    }
  *(u16x8*)(CbHb + ldsOff) = ph0;
  *(u16x8*)(CbLb + ldsOff) = pl0;
  __syncthreads();

  // ---------- Phase 3: VQ rounds (16 rows/wave; R1-proven round core) ----------
  bf16x8 bh0, bh1, bl0, bl1;
  float k2;
  {
    const float* kp = kfL + (wave * 16 + col) * 68 + quad * 8;
    float4 t0 = *(const float4*)(kp);
    float4 t1 = *(const float4*)(kp + 4);
    float4 t2 = *(const float4*)(kp + 32);
    float4 t3 = *(const float4*)(kp + 36);
    float fv[16];
    fv[0]=t0.x; fv[1]=t0.y; fv[2]=t0.z; fv[3]=t0.w;
    fv[4]=t1.x; fv[5]=t1.y; fv[6]=t1.z; fv[7]=t1.w;
    fv[8]=t2.x; fv[9]=t2.y; fv[10]=t2.z; fv[11]=t2.w;
    fv[12]=t3.x; fv[13]=t3.y; fv[14]=t3.z; fv[15]=t3.w;
    k2 = 0.f;
#pragma unroll
    for (int j = 0; j < 16; j++) k2 = fmaf(fv[j], fv[j], k2);
    k2 += __shfl_xor(k2, 16);
    k2 += __shfl_xor(k2, 32);
    u16x8 h0, h1, l0u, l1u;
#pragma unroll
    for (int j = 0; j < 8; j++) {
      unsigned short hi = f2bf(fv[j]);
      h0[j] = hi; l0u[j] = f2bf(fv[j] - bf2f(hi));
      unsigned short hi2 = f2bf(fv[8 + j]);
      h1[j] = hi2; l1u[j] = f2bf(fv[8 + j] - bf2f(hi2));
    }
    bh0 = __builtin_bit_cast(bf16x8, h0);
    bh1 = __builtin_bit_cast(bf16x8, h1);
    bl0 = __builtin_bit_cast(bf16x8, l0u);
    bl1 = __builtin_bit_cast(bf16x8, l1u);
  }
  float b1v = 1e38f, b2v = 1e38f;
  int b1i = 0x7fffffff, b2i = 0x7fffffff;
  for (int t = 0; t < 16; t++) {
    int cur = t & 1;
    u16x8 nh, nl;
    if (t < 15) {
      nh = *(const u16x8*)(gH + (t + 1) * 32 * HDD);
      nl = *(const u16x8*)(gL + (t + 1) * 32 * HDD);
    }
    const unsigned short* CbHc = CbHb + cur * 2304;
    const unsigned short* CbLc = CbLb + cur * 2304;
#pragma unroll
    for (int s = 0; s < 2; s++) {
      const unsigned short* rp = CbHc + (s * 16 + col) * 72 + quad * 8;
      const unsigned short* rq = CbLc + (s * 16 + col) * 72 + quad * 8;
      bf16x8 ah0 = *(const bf16x8*)(rp);
      bf16x8 ah1 = *(const bf16x8*)(rp + 32);
      bf16x8 al0 = *(const bf16x8*)(rq);
      bf16x8 al1 = *(const bf16x8*)(rq + 32);
      f32x4 aP = {}, aQ = {};
      aP = __builtin_amdgcn_mfma_f32_16x16x32_bf16(ah0, bh0, aP, 0, 0, 0);
      aQ = __builtin_amdgcn_mfma_f32_16x16x32_bf16(ah1, bh1, aQ, 0, 0, 0);
      aP = __builtin_amdgcn_mfma_f32_16x16x32_bf16(al0, bh0, aP, 0, 0, 0);
      aQ = __builtin_amdgcn_mfma_f32_16x16x32_bf16(al1, bh1, aQ, 0, 0, 0);
      aP = __builtin_amdgcn_mfma_f32_16x16x32_bf16(ah0, bl0, aP, 0, 0, 0);
      aQ = __builtin_amdgcn_mfma_f32_16x16x32_bf16(ah1, bl1, aQ, 0, 0, 0);
      f32x4 c2v = *(const f32x4*)(Cs + t * 32 + s * 16 + quad * 4);
#pragma unroll
      for (int r = 0; r < 4; r++) {
        float val = c2v[r] - 2.0f * (aP[r] + aQ[r]);
        int idx = t * 32 + s * 16 + quad * 4 + r;
        if (val < b1v) { b2v = b1v; b2i = b1i; b1v = val; b1i = idx; }
        else if (val < b2v) { b2v = val; b2i = idx; }
      }
    }
    if (t < 15) {
      *(u16x8*)(CbHb + (cur ^ 1) * 2304 + ldsOff) = nh;
      *(u16x8*)(CbLb + (cur ^ 1) * 2304 + ldsOff) = nl;
    }
    __syncthreads();
  }
#pragma unroll
  for (int d = 16; d <= 32; d <<= 1) {
    float o1v = __shfl_xor(b1v, d); int o1i = __shfl_xor(b1i, d);
    float o2v = __shfl_xor(b2v, d); int o2i = __shfl_xor(b2i, d);
    if (o1v < b1v || (o1v == b1v && o1i < b1i)) {
      float nv; int ni;
      if (b1v < o2v || (b1v == o2v && b1i < o2i)) { nv = b1v; ni = b1i; }
      else { nv = o2v; ni = o2i; }
      b1v = o1v; b1i = o1i; b2v = nv; b2i = ni;
    } else {
      if (o1v < b2v || (o1v == b2v && o1i < b2i)) { b2v = o1v; b2i = o1i; }
    }
  }
  const float DMARG = 0.015625f;
  bool trig = (b2v - b1v <= DMARG);
  float part;
  int widx = b1i;
  if (__any(trig)) {
    const float* kpr = kfL + (wave * 16 + col) * 68 + quad * 8;
    float4 f0 = *(const float4*)(kpr);
    float4 f1 = *(const float4*)(kpr + 4);
    float4 f2 = *(const float4*)(kpr + 32);
    float4 f3 = *(const float4*)(kpr + 36);
    const float* c1p = cb + ((long)h * NC + b1i) * HDD + quad * 8;
    const float* c2p = cb + ((long)h * NC + b2i) * HDD + quad * 8;
    float4 a0 = *(const float4*)(c1p);
    float4 a1 = *(const float4*)(c1p + 4);
    float4 a2 = *(const float4*)(c1p + 32);
    float4 a3 = *(const float4*)(c1p + 36);
    float4 e0 = *(const float4*)(c2p);
    float4 e1 = *(const float4*)(c2p + 4);
    float4 e2 = *(const float4*)(c2p + 32);
    float4 e3 = *(const float4*)(c2p + 36);
    float s1 = 0.f, s2 = 0.f;
#pragma unroll
    for (int j = 0; j < 4; j++) {
      float d;
      d = ((const float*)&f0)[j] - ((const float*)&a0)[j]; s1 = fmaf(d, d, s1);
      d = ((const float*)&f1)[j] - ((const float*)&a1)[j]; s1 = fmaf(d, d, s1);
      d = ((const float*)&f2)[j] - ((const float*)&a2)[j]; s1 = fmaf(d, d, s1);
      d = ((const float*)&f3)[j] - ((const float*)&a3)[j]; s1 = fmaf(d, d, s1);
      d = ((const float*)&f0)[j] - ((const float*)&e0)[j]; s2 = fmaf(d, d, s2);
      d = ((const float*)&f1)[j] - ((const float*)&e1)[j]; s2 = fmaf(d, d, s2);
      d = ((const float*)&f2)[j] - ((const float*)&e2)[j]; s2 = fmaf(d, d, s2);
      d = ((const float*)&f3)[j] - ((const float*)&e3)[j]; s2 = fmaf(d, d, s2);
    }
    s1 += __shfl_xor(s1, 16); s1 += __shfl_xor(s1, 32);
    s2 += __shfl_xor(s2, 16); s2 += __shfl_xor(s2, 32);
    if (trig) {
      if (s2 < s1 || (s2 == s1 && b2i < b1i)) { widx = b2i; part = s2; }
      else { widx = b1i; part = s1; }
    } else {
      part = k2 + b1v;
    }
  } else {
    part = k2 + b1v;
  }
  if (quad != 0) part = 0.f;
  part += __shfl_xor(part, 1);  part += __shfl_xor(part, 2);
  part += __shfl_xor(part, 4);  part += __shfl_xor(part, 8);
  part += __shfl_xor(part, 16); part += __shfl_xor(part, 32);
  if (lane == 0) atomicAdd(lsum, part);
  if (lane < 16)
    scodes[bh * LL + l0 + wave * 16 + lane] = (float)widx;
  // per-wave khat scatter via shfl (16 rows x 64 shorts)
  {
    int rL = lane >> 2;                 // 0..15
    int p = (lane & 3) * 16;
    int code = __shfl(widx, rL);        // lanes 0..15 hold widx for row=lane
    const unsigned short* src = cbbh + (long)code * HDD + p;
    unsigned short* dst = khat + (bh * LL + l0 + wave * 16 + rL) * HDD + p;
    *(u16x8*)(dst)     = *(const u16x8*)(src);
    *(u16x8*)(dst + 8) = *(const u16x8*)(src + 8);
  }
}

// ---------------- flash attention: paired q-tiles + swapped QK^T (key-major softmax) ----------------
__global__ __launch_bounds__(256) void attn_kernel(
    const unsigned short* __restrict__ qb, const unsigned short* __restrict__ khat,
    const unsigned short* __restrict__ vt, unsigned short* __restrict__ attnb) {
  __shared__ __align__(16) unsigned short Pbuf[4][2][16 * 72];  // 18432 B
  __shared__ __align__(16) unsigned short Kbuf[64 * 72];        // 9216 B
  __shared__ __align__(16) unsigned short Vbuf[64 * 72];        // 9216 B
  int tid = threadIdx.x, wave = tid >> 6, lane = tid & 63;
  int quad = lane >> 4, col = lane & 15;
  int id = blockIdx.y * 16 + blockIdx.x;
  int xcd = id & 7, sidx = id >> 3;
  int bh = xcd * 4 + (sidx >> 4);
  int pi = sidx & 15;
  int b = bh >> 4, h = bh & 15;
  int ta = pi, tb = 31 - pi;
  int qbA = ta * 64 + wave * 16;
  int qbB = tb * 64 + wave * 16;
  const unsigned short* qrA = qb + ((long)bh * LL + qbA + col) * HDD;
  const unsigned short* qrB = qb + ((long)bh * LL + qbB + col) * HDD;
  bf16x8 aqA0 = *(const bf16x8*)(qrA + quad * 8);
  bf16x8 aqA1 = *(const bf16x8*)(qrA + 32 + quad * 8);
  bf16x8 aqB0 = *(const bf16x8*)(qrB + quad * 8);
  bf16x8 aqB1 = *(const bf16x8*)(qrB + 32 + quad * 8);
  float lA = 0.f, lB = 0.f;
  f32x4 oA[4] = {}, oB[4] = {};
  unsigned short* PA = Pbuf[wave][0];
  unsigned short* PB = Pbuf[wave][1];
  const unsigned short* kh = khat + (long)bh * LL * HDD;
  const unsigned short* vh = vt + (long)bh * HDD * LL;
  int srow = tid >> 2, sc = (tid & 3) * 8;
  const unsigned short* gK = kh + (long)srow * HDD + sc;
  const unsigned short* gV = vh + (long)srow * LL + sc;
  unsigned short* lK = Kbuf + srow * 72 + sc;
  unsigned short* lV = Vbuf + srow * 72 + sc;
  const float SCL = 0.18033688011112042f;  // log2(e) / 8
  u16x8 rk0 = *(const u16x8*)(gK);
  u16x8 rk1 = *(const u16x8*)(gK + 32);
  u16x8 rv0 = *(const u16x8*)(gV);
  u16x8 rv1 = *(const u16x8*)(gV + 32);
  for (int kt = 0; kt <= tb; kt++) {
    int kbase = kt * 64;
    bool actA = (kt <= ta);
    __syncthreads();
    *(u16x8*)lK        = rk0;
    *(u16x8*)(lK + 32) = rk1;
    *(u16x8*)lV        = rv0;
    *(u16x8*)(lV + 32) = rv1;
    __syncthreads();
    if (kt < tb) {
      const unsigned short* nK = gK + (long)(kt + 1) * 64 * HDD;
      const unsigned short* nV = gV + (kt + 1) * 64;
      rk0 = *(const u16x8*)(nK);
      rk1 = *(const u16x8*)(nK + 32);
      rv0 = *(const u16x8*)(nV);
      rv1 = *(const u16x8*)(nV + 32);
    }
    f32x4 zA[4], zB[4];
    for (int nt = 0; nt < 4; nt++) {
      const unsigned short* krow = Kbuf + (nt * 16 + col) * 72;
      bf16x8 k0 = *(const bf16x8*)(krow + quad * 8);
      bf16x8 k1 = *(const bf16x8*)(krow + 32 + quad * 8);
      f32x4 z = {};
      z = __builtin_amdgcn_mfma_f32_16x16x32_bf16(k0, aqB0, z, 0, 0, 0);
      z = __builtin_amdgcn_mfma_f32_16x16x32_bf16(k1, aqB1, z, 0, 0, 0);
      zB[nt] = z;
      if (actA) {
        f32x4 y = {};
        y = __builtin_amdgcn_mfma_f32_16x16x32_bf16(k0, aqA0, y, 0, 0, 0);
        y = __builtin_amdgcn_mfma_f32_16x16x32_bf16(k1, aqA1, y, 0, 0, 0);
        zA[nt] = y;
      }
    }
    for (int nt = 0; nt < 4; nt++) {
      u16x4 pk;
      for (int r = 0; r < 4; r++) {
        float sc2 = zB[nt][r] * SCL;
        int key = kbase + nt * 16 + quad * 4 + r;
        if (kt == tb && key > qbB + col) sc2 = -1e30f;
        float p = exp2f(sc2);
        lB += p;
        pk[r] = __builtin_bit_cast(unsigned short, (__bf16)p);
      }
      *(u16x4*)(PB + col * 72 + nt * 16 + quad * 4) = pk;
    }
    if (actA) {
      for (int nt = 0; nt < 4; nt++) {
        u16x4 pk;
        for (int r = 0; r < 4; r++) {
          float sc2 = zA[nt][r] * SCL;
          int key = kbase + nt * 16 + quad * 4 + r;
          if (kt == ta && key > qbA + col) sc2 = -1e30f;
          float p = exp2f(sc2);
          lA += p;
          pk[r] = __builtin_bit_cast(unsigned short, (__bf16)p);
        }
        *(u16x4*)(PA + col * 72 + nt * 16 + quad * 4) = pk;
      }
    }
    bf16x8 apB0 = *(const bf16x8*)(PB + col * 72 + quad * 8);
    bf16x8 apB1 = *(const bf16x8*)(PB + col * 72 + 32 + quad * 8);
    bf16x8 apA0, apA1;
    if (actA) {
      apA0 = *(const bf16x8*)(PA + col * 72 + quad * 8);
      apA1 = *(const bf16x8*)(PA + col * 72 + 32 + quad * 8);
    }
    for (int nt = 0; nt < 4; nt++) {
      const unsigned short* vrow = Vbuf + (nt * 16 + col) * 72;
      bf16x8 v0 = *(const bf16x8*)(vrow + quad * 8);
      bf16x8 v1 = *(const bf16x8*)(vrow + 32 + quad * 8);
      oB[nt] = __builtin_amdgcn_mfma_f32_16x16x32_bf16(apB0, v0, oB[nt], 0, 0, 0);
      oB[nt] = __builtin_amdgcn_mfma_f32_16x16x32_bf16(apB1, v1, oB[nt], 0, 0, 0);
      if (actA) {
        oA[nt] = __builtin_amdgcn_mfma_f32_16x16x32_bf16(apA0, v0, oA[nt], 0, 0, 0);
        oA[nt] = __builtin_amdgcn_mfma_f32_16x16x32_bf16(apA1, v1, oA[nt], 0, 0, 0);
      }
    }
  }
  lA += __shfl_xor(lA, 16); lA += __shfl_xor(lA, 32);
  lB += __shfl_xor(lB, 16); lB += __shfl_xor(lB, 32);
  float invAc = 1.0f / lA;
  float invBc = 1.0f / lB;
  for (int r = 0; r < 4; r++) {
    float invA = __shfl(invAc, quad * 4 + r);
    float invB = __shfl(invBc, quad * 4 + r);
    int rowA = qbA + quad * 4 + r;
    int rowB = qbB + quad * 4 + r;
    for (int nt = 0; nt < 4; nt++) {
      int hd = nt * 16 + col;
      attnb[((long)b * LL + rowA) * DD + h * HDD + hd] = f2bf(oA[nt][r] * invA);
      attnb[((long)b * LL + rowB) * DD + h * HDD + hd] = f2bf(oB[nt][r] * invB);
    }
  }
}

// ---------------- GEMM2: out = attn * Wo^T, 128x64 tiles (512 blocks, 2/CU) ----------------
__global__ __launch_bounds__(256) void gemm_out(
    const unsigned short* __restrict__ attnb, const unsigned short* __restrict__ wob,
    float* __restrict__ out) {
  __shared__ __align__(16) unsigned short As[128 * 32];
  __shared__ __align__(16) unsigned short Bs[64 * 32];
  int tid = threadIdx.x;
  int wave = tid >> 6, lane = tid & 63;
  int quad = lane >> 4, col = lane & 15;
  int m0 = blockIdx.y * 128;
  int n0 = blockIdx.x * 64;
  f32x4 acc[4][2] = {};
  int row_in = (wave << 4) + (lane >> 2);
  int seg = lane & 3;
  const unsigned short* gA0 = attnb + (long)(m0 + row_in) * DD + seg * 8;
  const unsigned short* gA1 = attnb + (long)(m0 + 64 + row_in) * DD + seg * 8;
  const unsigned short* gB0 = wob + (long)(n0 + row_in) * DD + seg * 8;
  unsigned short* lA0 = As + wave * 512;
  unsigned short* lA1 = As + 2048 + wave * 512;
  unsigned short* lB0 = Bs + wave * 512;
  int wm = wave & 1, wn = wave >> 1;
  const unsigned short* pa = As + (wm * 64 + col) * 32 + quad * 8;
  const unsigned short* pb = Bs + (wn * 32 + col) * 32 + quad * 8;
  for (int kk = 0; kk < DD; kk += 32) {
    __syncthreads();
    load_lds16(gA0 + kk, lA0);
    load_lds16(gA1 + kk, lA1);
    load_lds16(gB0 + kk, lB0);
    __syncthreads();
    bf16x8 af[4], bfr[2];
    for (int t = 0; t < 4; t++) af[t]  = *(const bf16x8*)(pa + t * 512);
    for (int t = 0; t < 2; t++) bfr[t] = *(const bf16x8*)(pb + t * 512);
    for (int mt = 0; mt < 4; mt++)
      for (int nt = 0; nt < 2; nt++)
        acc[mt][nt] = __builtin_amdgcn_mfma_f32_16x16x32_bf16(af[mt], bfr[nt], acc[mt][nt], 0, 0, 0);
  }
  for (int mt = 0; mt < 4; mt++)
    for (int nt = 0; nt < 2; nt++) {
      int mbase = m0 + wm * 64 + mt * 16 + quad * 4;
      int n = n0 + wn * 32 + nt * 16 + col;
      for (int r = 0; r < 4; r++)
        out[(long)(mbase + r) * DD + n] = acc[mt][nt][r];
    }
}

// ---------------- finalize scalars ----------------
__global__ void finalize(const float* __restrict__ lsum, float* __restrict__ out) {
  if (threadIdx.x == 0) {
    float v = lsum[0] / (float)(BB * HH * LL);
    out[4194304] = v;
    out[4194305] = v;
  }
}

extern "C" void kernel_launch(void* const* d_in, const int* in_sizes, int n_in,
                              void* d_out, int out_size, void* d_ws, size_t ws_size,
                              hipStream_t stream) {
  const float* x  = (const float*)d_in[0];
  const float* wq = (const float*)d_in[1];
  const float* wk = (const float*)d_in[2];
  const float* wv = (const float*)d_in[3];
  const float* wo = (const float*)d_in[4];
  const float* cb = (const float*)d_in[5];
  float* out = (float*)d_out;

  char* ws = (char*)d_ws;
  size_t off = 0;
  auto alloc = [&](size_t bytes) {
    void* p = ws + off;
    off = (off + bytes + 255) & ~(size_t)255;
    return p;
  };
  unsigned short* xb    = (unsigned short*)alloc(4194304 * 2);
  unsigned short* xl    = (unsigned short*)alloc(4194304 * 2);
  unsigned short* wb    = (unsigned short*)alloc(3145728 * 2);
  unsigned short* wkl   = (unsigned short*)alloc(1048576 * 2);
  unsigned short* wob   = (unsigned short*)alloc(1048576 * 2);
  unsigned short* cbb   = (unsigned short*)alloc(524288 * 2);
  unsigned short* cbl   = (unsigned short*)alloc(524288 * 2);
  unsigned short* qb    = (unsigned short*)alloc(4194304 * 2);
  unsigned short* vt    = (unsigned short*)alloc(4194304 * 2);
  unsigned short* khat  = (unsigned short*)alloc(4194304 * 2);
  unsigned short* attnb = (unsigned short*)alloc(4194304 * 2);
  float* c2   = (float*)alloc(8192 * 4);
  float* lsum = (float*)alloc(256);

  cast_all<<<dim3(4128), dim3(256), 0, stream>>>(x, wq, wk, wv, wo, cb, xb, xl, wb, wkl, wob, cbb, cbl, c2, lsum);
  qv_kvq<<<dim3(1536), dim3(256), 0, stream>>>(xb, xl, wb, wkl, cb, c2, cbb, cbl, qb, vt, khat, out + 4194306, lsum);
  attn_kernel<<<dim3(16, 32), dim3(256), 0, stream>>>(qb, khat, vt, attnb);
  gemm_out<<<dim3(16, 32), dim3(256), 0, stream>>>(attnb, wob, out);
  finalize<<<dim3(1), dim3(64), 0, stream>>>(lsum, out);
}